// Round 1
// 1201.063 us; speedup vs baseline: 2.2859x; 2.2859x over previous
//
#include <hip/hip_runtime.h>
#include <stdint.h>

#define B_ 4
#define S_ 1024
#define D_ 1024
#define H_ 16
#define DK_ 64

// ---------------------------------------------------------------------------
// C = A @ W^T + bias. A: [M,K] f32 row-major. W: [N,K] f32 row-major.
// OMODE 0: C[m*N+n] f32. OMODE 1: scatter to [b][h][s][d] (m=b*S+s, n=h*64+d).
// Block: 256 threads -> 64x64 tile, thread computes 4x4. K-chunk = 16.
// ---------------------------------------------------------------------------
template <int OMODE>
__global__ __launch_bounds__(256) void gemm_bias(const float* __restrict__ A,
                                                 const float* __restrict__ W,
                                                 const float* __restrict__ bias,
                                                 float* __restrict__ Cout,
                                                 int M, int N, int K) {
    __shared__ float As[16][68];   // [k][m]
    __shared__ float Bs[16][68];   // [k][n]
    const int t  = threadIdx.x;
    const int m0 = blockIdx.y * 64;
    const int n0 = blockIdx.x * 64;
    const int tn = t & 15, tm = t >> 4;
    const int lr  = t >> 2;          // 0..63 load row
    const int lc  = (t & 3) * 4;     // 0,4,8,12 load col group
    float acc[4][4] = {};

    for (int kc = 0; kc < K; kc += 16) {
        {
            float4 u = *(const float4*)(A + (size_t)(m0 + lr) * K + kc + lc);
            As[lc + 0][lr] = u.x;
            As[lc + 1][lr] = u.y;
            As[lc + 2][lr] = u.z;
            As[lc + 3][lr] = u.w;
        }
        {
            float4 u = *(const float4*)(W + (size_t)(n0 + lr) * K + kc + lc);
            Bs[lc + 0][lr] = u.x;
            Bs[lc + 1][lr] = u.y;
            Bs[lc + 2][lr] = u.z;
            Bs[lc + 3][lr] = u.w;
        }
        __syncthreads();
#pragma unroll
        for (int kk = 0; kk < 16; ++kk) {
            float4 a = *(const float4*)&As[kk][tm * 4];
            float4 b = *(const float4*)&Bs[kk][tn * 4];
            float av[4] = {a.x, a.y, a.z, a.w};
            float bv[4] = {b.x, b.y, b.z, b.w};
#pragma unroll
            for (int i = 0; i < 4; ++i)
#pragma unroll
                for (int j = 0; j < 4; ++j) acc[i][j] += av[i] * bv[j];
        }
        __syncthreads();
    }

    const int nb = n0 + tn * 4;
    const float4 bv4 = *(const float4*)(bias + nb);
#pragma unroll
    for (int i = 0; i < 4; ++i) {
        const int m = m0 + tm * 4 + i;
        float4 o;
        o.x = acc[i][0] + bv4.x;
        o.y = acc[i][1] + bv4.y;
        o.z = acc[i][2] + bv4.z;
        o.w = acc[i][3] + bv4.w;
        if (OMODE == 0) {
            *(float4*)(Cout + (size_t)m * N + nb) = o;
        } else {
            const int b = m >> 10, s = m & (S_ - 1);
            const int h = nb >> 6, d = nb & 63;
            *(float4*)(Cout + (((size_t)b * H_ + h) * S_ + s) * DK_ + d) = o;
        }
    }
}

// ---------------------------------------------------------------------------
// Raw scores = Qh @ Kh^T per (b,h), written fp32 into the attn output region
// in [h*B+b][i][j] layout. Batched version of the gemm_bias tile (K = 64).
// Grid: (16 j-tiles, 16 i-tiles, 64 bh). Block 256 -> 64x64 tile, 4x4 micro.
// ---------------------------------------------------------------------------
__global__ __launch_bounds__(256) void scores_gemm(const float* __restrict__ Qh,
                                                   const float* __restrict__ Kh,
                                                   float* __restrict__ Sc) {
    const int bh = blockIdx.z;           // b*H + h
    const int b = bh >> 4, h = bh & 15;
    const float* A = Qh + (size_t)bh * S_ * DK_;
    const float* W = Kh + (size_t)bh * S_ * DK_;
    float* C = Sc + (size_t)(h * B_ + b) * S_ * S_;

    __shared__ float As[16][68];   // [k][m]
    __shared__ float Bs[16][68];   // [k][n]
    const int t  = threadIdx.x;
    const int m0 = blockIdx.y * 64;
    const int n0 = blockIdx.x * 64;
    const int tn = t & 15, tm = t >> 4;
    const int lr = t >> 2;           // 0..63 load row
    const int lc = (t & 3) * 4;      // 0,4,8,12 load col group
    float acc[4][4] = {};

    for (int kc = 0; kc < DK_; kc += 16) {
        {
            float4 u = *(const float4*)(A + (size_t)(m0 + lr) * DK_ + kc + lc);
            As[lc + 0][lr] = u.x;
            As[lc + 1][lr] = u.y;
            As[lc + 2][lr] = u.z;
            As[lc + 3][lr] = u.w;
        }
        {
            float4 u = *(const float4*)(W + (size_t)(n0 + lr) * DK_ + kc + lc);
            Bs[lc + 0][lr] = u.x;
            Bs[lc + 1][lr] = u.y;
            Bs[lc + 2][lr] = u.z;
            Bs[lc + 3][lr] = u.w;
        }
        __syncthreads();
#pragma unroll
        for (int kk = 0; kk < 16; ++kk) {
            float4 a = *(const float4*)&As[kk][tm * 4];
            float4 b2 = *(const float4*)&Bs[kk][tn * 4];
            float av[4] = {a.x, a.y, a.z, a.w};
            float bv[4] = {b2.x, b2.y, b2.z, b2.w};
#pragma unroll
            for (int i = 0; i < 4; ++i)
#pragma unroll
                for (int j = 0; j < 4; ++j) acc[i][j] += av[i] * bv[j];
        }
        __syncthreads();
    }

    const int nb = n0 + tn * 4;
#pragma unroll
    for (int i = 0; i < 4; ++i) {
        const int m = m0 + tm * 4 + i;
        *(float4*)(C + (size_t)m * S_ + nb) =
            make_float4(acc[i][0], acc[i][1], acc[i][2], acc[i][3]);
    }
}

// ---------------------------------------------------------------------------
// In-place row softmax over the attn region. One block per row of 1024.
// Replay-safe: scores_gemm regenerates the raw scores on every replay.
// ---------------------------------------------------------------------------
__global__ __launch_bounds__(256) void softmax_rows(float* __restrict__ attn) {
    const size_t row = blockIdx.x;
    float* p = attn + row * S_;
    const int t = threadIdx.x;

    float4 v = ((const float4*)p)[t];
    float mx = fmaxf(fmaxf(v.x, v.y), fmaxf(v.z, v.w));
#pragma unroll
    for (int o = 32; o > 0; o >>= 1) mx = fmaxf(mx, __shfl_xor(mx, o, 64));

    __shared__ float red[8];
    const int w = t >> 6;
    if ((t & 63) == 0) red[w] = mx;
    __syncthreads();
    mx = fmaxf(fmaxf(red[0], red[1]), fmaxf(red[2], red[3]));

    float4 e;
    e.x = __expf(v.x - mx);
    e.y = __expf(v.y - mx);
    e.z = __expf(v.z - mx);
    e.w = __expf(v.w - mx);
    float s = e.x + e.y + e.z + e.w;
#pragma unroll
    for (int o = 32; o > 0; o >>= 1) s += __shfl_xor(s, o, 64);
    if ((t & 63) == 0) red[4 + w] = s;
    __syncthreads();
    s = red[4] + red[5] + red[6] + red[7];

    const float inv = 1.0f / s;
    e.x *= inv; e.y *= inv; e.z *= inv; e.w *= inv;
    ((float4*)p)[t] = e;
}

// ---------------------------------------------------------------------------
// ctx = attn @ V per (b,h). attn read back fp32 from the output region.
// Block: 256 thr computes 32 rows x 64 d tile. Output -> ctx[b][s][h*64+d].
// ---------------------------------------------------------------------------
__global__ __launch_bounds__(256) void attn_pv(const float* __restrict__ attn,
                                               const float* __restrict__ Vh,
                                               float* __restrict__ ctx) {
    const int bh = blockIdx.y;
    const int b = bh >> 4, h = bh & 15;
    const int i0 = blockIdx.x * 32;
    const int t  = threadIdx.x;
    const int i  = t & 31;
    const int d0 = (t >> 5) * 8;

    __shared__ float As[32][33];
    __shared__ float Vs[32][64];

    float acc[8] = {};
    const float* abase = attn + ((size_t)(h * B_ + b) * S_ + i0) * S_;
    const float* vbase = Vh + (size_t)bh * S_ * DK_;
    const int lr  = t >> 3;          // 0..31
    const int lc4 = (t & 7) * 4;
    const int lc8 = (t & 7) * 8;

    for (int jc = 0; jc < 32; ++jc) {
        const int j0 = jc * 32;
        {
            float4 u = *(const float4*)(abase + (size_t)lr * S_ + j0 + lc4);
            As[lr][lc4 + 0] = u.x;
            As[lr][lc4 + 1] = u.y;
            As[lr][lc4 + 2] = u.z;
            As[lr][lc4 + 3] = u.w;
        }
        {
            const float4* vp = (const float4*)(vbase + (size_t)(j0 + lr) * DK_ + lc8);
            float4 v0 = vp[0], v1 = vp[1];
            *(float4*)&Vs[lr][lc8]     = v0;
            *(float4*)&Vs[lr][lc8 + 4] = v1;
        }
        __syncthreads();
#pragma unroll
        for (int jj = 0; jj < 32; ++jj) {
            const float a = As[i][jj];
            float4 v0 = *(const float4*)&Vs[jj][d0];
            float4 v1 = *(const float4*)&Vs[jj][d0 + 4];
            acc[0] += a * v0.x; acc[1] += a * v0.y; acc[2] += a * v0.z; acc[3] += a * v0.w;
            acc[4] += a * v1.x; acc[5] += a * v1.y; acc[6] += a * v1.z; acc[7] += a * v1.w;
        }
        __syncthreads();
    }
    float* crow = ctx + ((size_t)b * S_ + i0 + i) * D_ + h * DK_ + d0;
    *(float4*)crow       = make_float4(acc[0], acc[1], acc[2], acc[3]);
    *(float4*)(crow + 4) = make_float4(acc[4], acc[5], acc[6], acc[7]);
}

// ---------------------------------------------------------------------------
// y = LayerNorm(x + residual_q) * gamma + beta  (one block per row of 1024)
// ---------------------------------------------------------------------------
__global__ __launch_bounds__(256) void ln_kernel(const float* __restrict__ X,
                                                 const float* __restrict__ q,
                                                 const float* __restrict__ gamma,
                                                 const float* __restrict__ beta,
                                                 float* __restrict__ y) {
    const int row = blockIdx.x;
    const int t   = threadIdx.x;
    const size_t base = (size_t)row * D_;

    float4 xv = *(const float4*)(X + base + t * 4);
    float4 qv = *(const float4*)(q + base + t * 4);
    const float x0 = xv.x + qv.x, x1 = xv.y + qv.y;
    const float x2 = xv.z + qv.z, x3 = xv.w + qv.w;

    float sum = x0 + x1 + x2 + x3;
    float sq  = x0 * x0 + x1 * x1 + x2 * x2 + x3 * x3;
#pragma unroll
    for (int o = 32; o > 0; o >>= 1) {
        sum += __shfl_xor(sum, o, 64);
        sq  += __shfl_xor(sq, o, 64);
    }
    __shared__ float red[8];
    const int wv = t >> 6;
    if ((t & 63) == 0) { red[wv] = sum; red[4 + wv] = sq; }
    __syncthreads();
    sum = red[0] + red[1] + red[2] + red[3];
    sq  = red[4] + red[5] + red[6] + red[7];

    const float mu  = sum * (1.0f / 1024.0f);
    const float var = sq * (1.0f / 1024.0f) - mu * mu;
    const float rs  = rsqrtf(var + 1e-5f);

    float4 gv = *(const float4*)(gamma + t * 4);
    float4 bv = *(const float4*)(beta + t * 4);
    float4 o;
    o.x = (x0 - mu) * rs * gv.x + bv.x;
    o.y = (x1 - mu) * rs * gv.y + bv.y;
    o.z = (x2 - mu) * rs * gv.z + bv.z;
    o.w = (x3 - mu) * rs * gv.w + bv.w;
    *(float4*)(y + base + t * 4) = o;
}

extern "C" void kernel_launch(void* const* d_in, const int* in_sizes, int n_in,
                              void* d_out, int out_size, void* d_ws, size_t ws_size,
                              hipStream_t stream) {
    const float* q    = (const float*)d_in[0];
    const float* k    = (const float*)d_in[1];
    const float* v    = (const float*)d_in[2];
    const float* Wq   = (const float*)d_in[3];
    const float* bq   = (const float*)d_in[4];
    const float* Wk   = (const float*)d_in[5];
    const float* bk   = (const float*)d_in[6];
    const float* Wv   = (const float*)d_in[7];
    const float* bv   = (const float*)d_in[8];
    const float* Wfc  = (const float*)d_in[9];
    const float* bfc  = (const float*)d_in[10];
    const float* gamma= (const float*)d_in[11];
    const float* beta = (const float*)d_in[12];

    float* y_out    = (float*)d_out;
    float* attn_out = (float*)d_out + (size_t)B_ * S_ * D_;   // fp32 outputs

    // Workspace (48 MB): Qh/Kh/Vh, then reuse Kh->ctx, Qh->xbuf.
    float* ws   = (float*)d_ws;
    float* Qh   = ws;                 // 16 MB  [b][h][s][64]
    float* Kh   = ws + 4194304;       // 16 MB  [b][h][s][64]
    float* Vh   = ws + 8388608;       // 16 MB  [b][h][s][64]
    float* ctx  = Kh;                 // reuse (Kh dead after scores_gemm)
    float* xbuf = Qh;                 // reuse (Qh dead after scores_gemm)

    const dim3 gg(16, 64), bb(256);
    gemm_bias<1><<<gg, bb, 0, stream>>>(q, Wq, bq, Qh, 4096, 1024, 1024);
    gemm_bias<1><<<gg, bb, 0, stream>>>(k, Wk, bk, Kh, 4096, 1024, 1024);
    gemm_bias<1><<<gg, bb, 0, stream>>>(v, Wv, bv, Vh, 4096, 1024, 1024);

    // scores -> attn region (raw), then in-place softmax
    scores_gemm<<<dim3(16, 16, 64), bb, 0, stream>>>(Qh, Kh, attn_out);
    softmax_rows<<<dim3(B_ * H_ * S_), bb, 0, stream>>>(attn_out);

    attn_pv<<<dim3(32, 64), 256, 0, stream>>>(attn_out, Vh, ctx);

    gemm_bias<0><<<gg, bb, 0, stream>>>(ctx, Wfc, bfc, xbuf, 4096, 1024, 1024);
    ln_kernel<<<4096, 256, 0, stream>>>(xbuf, q, gamma, beta, y_out);
}

// Round 2
// 1065.379 us; speedup vs baseline: 2.5770x; 1.1274x over previous
//
#include <hip/hip_runtime.h>
#include <stdint.h>

#define B_ 4
#define S_ 1024
#define D_ 1024
#define H_ 16
#define DK_ 64

// ---------------------------------------------------------------------------
// C = A @ W^T + bias. A: [M,K] f32 row-major. W: [N,K] f32 row-major.
// OMODE 0: C[m*N+n]. OMODE 1: scatter to [b][h][s][d] (m=b*S+s, n=h*64+d).
// Block 256 -> 128x128 tile, thread computes 8x8 (cols split tn*4 / 64+tn*4
// so LDS B-reads are 2-way max). K-chunk 16, register prefetch of next chunk.
// ---------------------------------------------------------------------------
template <int OMODE>
__global__ __launch_bounds__(256) void gemm_bias(const float* __restrict__ A,
                                                 const float* __restrict__ W,
                                                 const float* __restrict__ bias,
                                                 float* __restrict__ Cout,
                                                 int M, int N, int K) {
    __shared__ float As[16][132];   // [k][m], stride 132 -> 2-way stores max
    __shared__ float Bs[16][132];   // [k][n]
    const int t  = threadIdx.x;
    const int m0 = blockIdx.y * 128;
    const int n0 = blockIdx.x * 128;
    const int tm = t >> 4;           // 0..15 row group (8 rows)
    const int tn = t & 15;           // 0..15 col group (4+4 cols)
    const int srow = t >> 2;         // 0..63 staging row
    const int scg  = (t & 3) * 4;    // staging k-group

    const float* Ab0 = A + (size_t)(m0 + srow) * K + scg;
    const float* Ab1 = A + (size_t)(m0 + srow + 64) * K + scg;
    const float* Wb0 = W + (size_t)(n0 + srow) * K + scg;
    const float* Wb1 = W + (size_t)(n0 + srow + 64) * K + scg;

    float4 pa0 = *(const float4*)Ab0;
    float4 pa1 = *(const float4*)Ab1;
    float4 pb0 = *(const float4*)Wb0;
    float4 pb1 = *(const float4*)Wb1;

    float acc[8][8] = {};

    for (int kc = 0; kc < K; kc += 16) {
        As[scg + 0][srow]      = pa0.x;
        As[scg + 1][srow]      = pa0.y;
        As[scg + 2][srow]      = pa0.z;
        As[scg + 3][srow]      = pa0.w;
        As[scg + 0][srow + 64] = pa1.x;
        As[scg + 1][srow + 64] = pa1.y;
        As[scg + 2][srow + 64] = pa1.z;
        As[scg + 3][srow + 64] = pa1.w;
        Bs[scg + 0][srow]      = pb0.x;
        Bs[scg + 1][srow]      = pb0.y;
        Bs[scg + 2][srow]      = pb0.z;
        Bs[scg + 3][srow]      = pb0.w;
        Bs[scg + 0][srow + 64] = pb1.x;
        Bs[scg + 1][srow + 64] = pb1.y;
        Bs[scg + 2][srow + 64] = pb1.z;
        Bs[scg + 3][srow + 64] = pb1.w;
        __syncthreads();
        if (kc + 16 < K) {           // prefetch next chunk (hidden under MACs)
            pa0 = *(const float4*)(Ab0 + kc + 16);
            pa1 = *(const float4*)(Ab1 + kc + 16);
            pb0 = *(const float4*)(Wb0 + kc + 16);
            pb1 = *(const float4*)(Wb1 + kc + 16);
        }
#pragma unroll
        for (int kk = 0; kk < 16; ++kk) {
            float4 a0 = *(const float4*)&As[kk][tm * 8];
            float4 a1 = *(const float4*)&As[kk][tm * 8 + 4];
            float4 b0 = *(const float4*)&Bs[kk][tn * 4];
            float4 b1 = *(const float4*)&Bs[kk][64 + tn * 4];
            float av[8] = {a0.x, a0.y, a0.z, a0.w, a1.x, a1.y, a1.z, a1.w};
            float bv[8] = {b0.x, b0.y, b0.z, b0.w, b1.x, b1.y, b1.z, b1.w};
#pragma unroll
            for (int i = 0; i < 8; ++i)
#pragma unroll
                for (int j = 0; j < 8; ++j) acc[i][j] += av[i] * bv[j];
        }
        __syncthreads();
    }

    const int nb0 = n0 + tn * 4;
    const int nb1 = n0 + 64 + tn * 4;
    const float4 bi0 = *(const float4*)(bias + nb0);
    const float4 bi1 = *(const float4*)(bias + nb1);
#pragma unroll
    for (int i = 0; i < 8; ++i) {
        const int m = m0 + tm * 8 + i;
        float4 o0 = make_float4(acc[i][0] + bi0.x, acc[i][1] + bi0.y,
                                acc[i][2] + bi0.z, acc[i][3] + bi0.w);
        float4 o1 = make_float4(acc[i][4] + bi1.x, acc[i][5] + bi1.y,
                                acc[i][6] + bi1.z, acc[i][7] + bi1.w);
        if (OMODE == 0) {
            *(float4*)(Cout + (size_t)m * N + nb0) = o0;
            *(float4*)(Cout + (size_t)m * N + nb1) = o1;
        } else {
            const int b = m >> 10, s = m & (S_ - 1);
            const int h0 = nb0 >> 6, d0 = nb0 & 63;
            const int h1 = nb1 >> 6, d1 = nb1 & 63;
            *(float4*)(Cout + (((size_t)b * H_ + h0) * S_ + s) * DK_ + d0) = o0;
            *(float4*)(Cout + (((size_t)b * H_ + h1) * S_ + s) * DK_ + d1) = o1;
        }
    }
}

// ---------------------------------------------------------------------------
// Raw scores = Qh @ Kh^T per (b,h) -> [h*B+b][i][j] fp32 in attn region.
// Same 128x128 / 8x8 structure, K = 64. Grid (8, 8, 64).
// ---------------------------------------------------------------------------
__global__ __launch_bounds__(256) void scores_gemm(const float* __restrict__ Qh,
                                                   const float* __restrict__ Kh,
                                                   float* __restrict__ Sc) {
    const int bh = blockIdx.z;
    const int b = bh >> 4, h = bh & 15;
    const float* A = Qh + (size_t)bh * S_ * DK_;
    const float* W = Kh + (size_t)bh * S_ * DK_;
    float* C = Sc + (size_t)(h * B_ + b) * S_ * S_;

    __shared__ float As[16][132];
    __shared__ float Bs[16][132];
    const int t  = threadIdx.x;
    const int m0 = blockIdx.y * 128;
    const int n0 = blockIdx.x * 128;
    const int tm = t >> 4;
    const int tn = t & 15;
    const int srow = t >> 2;
    const int scg  = (t & 3) * 4;

    const float* Ab0 = A + (size_t)(m0 + srow) * DK_ + scg;
    const float* Ab1 = A + (size_t)(m0 + srow + 64) * DK_ + scg;
    const float* Wb0 = W + (size_t)(n0 + srow) * DK_ + scg;
    const float* Wb1 = W + (size_t)(n0 + srow + 64) * DK_ + scg;

    float4 pa0 = *(const float4*)Ab0;
    float4 pa1 = *(const float4*)Ab1;
    float4 pb0 = *(const float4*)Wb0;
    float4 pb1 = *(const float4*)Wb1;

    float acc[8][8] = {};

    for (int kc = 0; kc < DK_; kc += 16) {
        As[scg + 0][srow]      = pa0.x;
        As[scg + 1][srow]      = pa0.y;
        As[scg + 2][srow]      = pa0.z;
        As[scg + 3][srow]      = pa0.w;
        As[scg + 0][srow + 64] = pa1.x;
        As[scg + 1][srow + 64] = pa1.y;
        As[scg + 2][srow + 64] = pa1.z;
        As[scg + 3][srow + 64] = pa1.w;
        Bs[scg + 0][srow]      = pb0.x;
        Bs[scg + 1][srow]      = pb0.y;
        Bs[scg + 2][srow]      = pb0.z;
        Bs[scg + 3][srow]      = pb0.w;
        Bs[scg + 0][srow + 64] = pb1.x;
        Bs[scg + 1][srow + 64] = pb1.y;
        Bs[scg + 2][srow + 64] = pb1.z;
        Bs[scg + 3][srow + 64] = pb1.w;
        __syncthreads();
        if (kc + 16 < DK_) {
            pa0 = *(const float4*)(Ab0 + kc + 16);
            pa1 = *(const float4*)(Ab1 + kc + 16);
            pb0 = *(const float4*)(Wb0 + kc + 16);
            pb1 = *(const float4*)(Wb1 + kc + 16);
        }
#pragma unroll
        for (int kk = 0; kk < 16; ++kk) {
            float4 a0 = *(const float4*)&As[kk][tm * 8];
            float4 a1 = *(const float4*)&As[kk][tm * 8 + 4];
            float4 b0 = *(const float4*)&Bs[kk][tn * 4];
            float4 b1 = *(const float4*)&Bs[kk][64 + tn * 4];
            float av[8] = {a0.x, a0.y, a0.z, a0.w, a1.x, a1.y, a1.z, a1.w};
            float bv[8] = {b0.x, b0.y, b0.z, b0.w, b1.x, b1.y, b1.z, b1.w};
#pragma unroll
            for (int i = 0; i < 8; ++i)
#pragma unroll
                for (int j = 0; j < 8; ++j) acc[i][j] += av[i] * bv[j];
        }
        __syncthreads();
    }

    const int nb0 = n0 + tn * 4;
    const int nb1 = n0 + 64 + tn * 4;
#pragma unroll
    for (int i = 0; i < 8; ++i) {
        const int m = m0 + tm * 8 + i;
        *(float4*)(C + (size_t)m * S_ + nb0) =
            make_float4(acc[i][0], acc[i][1], acc[i][2], acc[i][3]);
        *(float4*)(C + (size_t)m * S_ + nb1) =
            make_float4(acc[i][4], acc[i][5], acc[i][6], acc[i][7]);
    }
}

// ---------------------------------------------------------------------------
// In-place row softmax over the attn region. One block per row of 1024.
// Replay-safe: scores_gemm regenerates raw scores on every replay.
// ---------------------------------------------------------------------------
__global__ __launch_bounds__(256) void softmax_rows(float* __restrict__ attn) {
    const size_t row = blockIdx.x;
    float* p = attn + row * S_;
    const int t = threadIdx.x;

    float4 v = ((const float4*)p)[t];
    float mx = fmaxf(fmaxf(v.x, v.y), fmaxf(v.z, v.w));
#pragma unroll
    for (int o = 32; o > 0; o >>= 1) mx = fmaxf(mx, __shfl_xor(mx, o, 64));

    __shared__ float red[8];
    const int w = t >> 6;
    if ((t & 63) == 0) red[w] = mx;
    __syncthreads();
    mx = fmaxf(fmaxf(red[0], red[1]), fmaxf(red[2], red[3]));

    float4 e;
    e.x = __expf(v.x - mx);
    e.y = __expf(v.y - mx);
    e.z = __expf(v.z - mx);
    e.w = __expf(v.w - mx);
    float s = e.x + e.y + e.z + e.w;
#pragma unroll
    for (int o = 32; o > 0; o >>= 1) s += __shfl_xor(s, o, 64);
    if ((t & 63) == 0) red[4 + w] = s;
    __syncthreads();
    s = red[4] + red[5] + red[6] + red[7];

    const float inv = 1.0f / s;
    e.x *= inv; e.y *= inv; e.z *= inv; e.w *= inv;
    ((float4*)p)[t] = e;
}

// ---------------------------------------------------------------------------
// ctx = attn @ V per (b,h). 256x64 tile per block, 8x8 micro (cols split
// tn*4 / 32+tn*4). K-chunk 16 with register prefetch. Grid (4, 64).
// Output -> ctx[b][s][h*64+d].
// ---------------------------------------------------------------------------
__global__ __launch_bounds__(256) void attn_pv(const float* __restrict__ attn,
                                               const float* __restrict__ Vh,
                                               float* __restrict__ ctx) {
    const int bh = blockIdx.y;
    const int b = bh >> 4, h = bh & 15;
    const int i0 = blockIdx.x * 256;
    const int t  = threadIdx.x;
    const int tm = t >> 3;           // 0..31 row group (8 rows)
    const int tn = t & 7;            // 0..7 col group (4+4 cols)
    const int srow = t >> 2;         // 0..63 (+64r)
    const int scg  = (t & 3) * 4;
    const int vrow = t >> 4;         // 0..15
    const int vcg  = (t & 15) * 4;

    __shared__ float As[16][260];    // [k][i]
    __shared__ float Vs[16][68];     // [k][d]

    const float* abase = attn + ((size_t)(h * B_ + b) * S_ + i0) * S_;
    const float* vbase = Vh + (size_t)bh * S_ * DK_;

    const float* Ar0 = abase + (size_t)(srow)       * S_ + scg;
    const float* Ar1 = abase + (size_t)(srow + 64)  * S_ + scg;
    const float* Ar2 = abase + (size_t)(srow + 128) * S_ + scg;
    const float* Ar3 = abase + (size_t)(srow + 192) * S_ + scg;
    const float* Vr  = vbase + (size_t)vrow * DK_ + vcg;

    float4 pa0 = *(const float4*)Ar0;
    float4 pa1 = *(const float4*)Ar1;
    float4 pa2 = *(const float4*)Ar2;
    float4 pa3 = *(const float4*)Ar3;
    float4 pv  = *(const float4*)Vr;

    float acc[8][8] = {};

    for (int kc = 0; kc < S_; kc += 16) {
        As[scg + 0][srow]       = pa0.x;
        As[scg + 1][srow]       = pa0.y;
        As[scg + 2][srow]       = pa0.z;
        As[scg + 3][srow]       = pa0.w;
        As[scg + 0][srow + 64]  = pa1.x;
        As[scg + 1][srow + 64]  = pa1.y;
        As[scg + 2][srow + 64]  = pa1.z;
        As[scg + 3][srow + 64]  = pa1.w;
        As[scg + 0][srow + 128] = pa2.x;
        As[scg + 1][srow + 128] = pa2.y;
        As[scg + 2][srow + 128] = pa2.z;
        As[scg + 3][srow + 128] = pa2.w;
        As[scg + 0][srow + 192] = pa3.x;
        As[scg + 1][srow + 192] = pa3.y;
        As[scg + 2][srow + 192] = pa3.z;
        As[scg + 3][srow + 192] = pa3.w;
        *(float4*)&Vs[vrow][vcg] = pv;
        __syncthreads();
        if (kc + 16 < S_) {
            pa0 = *(const float4*)(Ar0 + kc + 16);
            pa1 = *(const float4*)(Ar1 + kc + 16);
            pa2 = *(const float4*)(Ar2 + kc + 16);
            pa3 = *(const float4*)(Ar3 + kc + 16);
            pv  = *(const float4*)(Vr + (size_t)(kc + 16) * DK_);
        }
#pragma unroll
        for (int kk = 0; kk < 16; ++kk) {
            float4 a0 = *(const float4*)&As[kk][tm * 8];
            float4 a1 = *(const float4*)&As[kk][tm * 8 + 4];
            float4 v0 = *(const float4*)&Vs[kk][tn * 4];
            float4 v1 = *(const float4*)&Vs[kk][32 + tn * 4];
            float av[8] = {a0.x, a0.y, a0.z, a0.w, a1.x, a1.y, a1.z, a1.w};
            float vv[8] = {v0.x, v0.y, v0.z, v0.w, v1.x, v1.y, v1.z, v1.w};
#pragma unroll
            for (int i = 0; i < 8; ++i)
#pragma unroll
                for (int j = 0; j < 8; ++j) acc[i][j] += av[i] * vv[j];
        }
        __syncthreads();
    }

#pragma unroll
    for (int i = 0; i < 8; ++i) {
        const int m = i0 + tm * 8 + i;
        float* crow = ctx + ((size_t)b * S_ + m) * D_ + h * DK_;
        *(float4*)(crow + tn * 4) =
            make_float4(acc[i][0], acc[i][1], acc[i][2], acc[i][3]);
        *(float4*)(crow + 32 + tn * 4) =
            make_float4(acc[i][4], acc[i][5], acc[i][6], acc[i][7]);
    }
}

// ---------------------------------------------------------------------------
// y = LayerNorm(x + residual_q) * gamma + beta  (one block per row of 1024)
// ---------------------------------------------------------------------------
__global__ __launch_bounds__(256) void ln_kernel(const float* __restrict__ X,
                                                 const float* __restrict__ q,
                                                 const float* __restrict__ gamma,
                                                 const float* __restrict__ beta,
                                                 float* __restrict__ y) {
    const int row = blockIdx.x;
    const int t   = threadIdx.x;
    const size_t base = (size_t)row * D_;

    float4 xv = *(const float4*)(X + base + t * 4);
    float4 qv = *(const float4*)(q + base + t * 4);
    const float x0 = xv.x + qv.x, x1 = xv.y + qv.y;
    const float x2 = xv.z + qv.z, x3 = xv.w + qv.w;

    float sum = x0 + x1 + x2 + x3;
    float sq  = x0 * x0 + x1 * x1 + x2 * x2 + x3 * x3;
#pragma unroll
    for (int o = 32; o > 0; o >>= 1) {
        sum += __shfl_xor(sum, o, 64);
        sq  += __shfl_xor(sq, o, 64);
    }
    __shared__ float red[8];
    const int wv = t >> 6;
    if ((t & 63) == 0) { red[wv] = sum; red[4 + wv] = sq; }
    __syncthreads();
    sum = red[0] + red[1] + red[2] + red[3];
    sq  = red[4] + red[5] + red[6] + red[7];

    const float mu  = sum * (1.0f / 1024.0f);
    const float var = sq * (1.0f / 1024.0f) - mu * mu;
    const float rs  = rsqrtf(var + 1e-5f);

    float4 gv = *(const float4*)(gamma + t * 4);
    float4 bv = *(const float4*)(beta + t * 4);
    float4 o;
    o.x = (x0 - mu) * rs * gv.x + bv.x;
    o.y = (x1 - mu) * rs * gv.y + bv.y;
    o.z = (x2 - mu) * rs * gv.z + bv.z;
    o.w = (x3 - mu) * rs * gv.w + bv.w;
    *(float4*)(y + base + t * 4) = o;
}

extern "C" void kernel_launch(void* const* d_in, const int* in_sizes, int n_in,
                              void* d_out, int out_size, void* d_ws, size_t ws_size,
                              hipStream_t stream) {
    const float* q    = (const float*)d_in[0];
    const float* k    = (const float*)d_in[1];
    const float* v    = (const float*)d_in[2];
    const float* Wq   = (const float*)d_in[3];
    const float* bq   = (const float*)d_in[4];
    const float* Wk   = (const float*)d_in[5];
    const float* bk   = (const float*)d_in[6];
    const float* Wv   = (const float*)d_in[7];
    const float* bv   = (const float*)d_in[8];
    const float* Wfc  = (const float*)d_in[9];
    const float* bfc  = (const float*)d_in[10];
    const float* gamma= (const float*)d_in[11];
    const float* beta = (const float*)d_in[12];

    float* y_out    = (float*)d_out;
    float* attn_out = (float*)d_out + (size_t)B_ * S_ * D_;   // fp32 outputs

    // Workspace (48 MB): Qh/Kh/Vh, then reuse Kh->ctx, Qh->xbuf.
    float* ws   = (float*)d_ws;
    float* Qh   = ws;                 // 16 MB  [b][h][s][64]
    float* Kh   = ws + 4194304;       // 16 MB  [b][h][s][64]
    float* Vh   = ws + 8388608;       // 16 MB  [b][h][s][64]
    float* ctx  = Kh;                 // reuse (Kh dead after scores_gemm)
    float* xbuf = Qh;                 // reuse (Qh dead after scores_gemm)

    const dim3 gg(8, 32), bb(256);    // 128x128 tiles: N/128=8, M/128=32
    gemm_bias<1><<<gg, bb, 0, stream>>>(q, Wq, bq, Qh, 4096, 1024, 1024);
    gemm_bias<1><<<gg, bb, 0, stream>>>(k, Wk, bk, Kh, 4096, 1024, 1024);
    gemm_bias<1><<<gg, bb, 0, stream>>>(v, Wv, bv, Vh, 4096, 1024, 1024);

    scores_gemm<<<dim3(8, 8, 64), bb, 0, stream>>>(Qh, Kh, attn_out);
    softmax_rows<<<dim3(B_ * H_ * S_), bb, 0, stream>>>(attn_out);

    attn_pv<<<dim3(4, 64), bb, 0, stream>>>(attn_out, Vh, ctx);

    gemm_bias<0><<<gg, bb, 0, stream>>>(ctx, Wfc, bfc, xbuf, 4096, 1024, 1024);
    ln_kernel<<<4096, 256, 0, stream>>>(xbuf, q, gamma, beta, y_out);
}

// Round 4
// 809.813 us; speedup vs baseline: 3.3903x; 1.3156x over previous
//
#include <hip/hip_runtime.h>
#include <stdint.h>

#define B_ 4
#define S_ 1024
#define D_ 1024
#define H_ 16
#define DK_ 64

typedef unsigned short u16;
typedef unsigned int   u32;
typedef short bf16x8 __attribute__((ext_vector_type(8)));
typedef float f32x4  __attribute__((ext_vector_type(4)));

__device__ __forceinline__ u16 f2bf(float x) {            // RNE fp32 -> bf16
    u32 u = __float_as_uint(x);
    return (u16)((u + 0x7fffu + ((u >> 16) & 1u)) >> 16);
}
__device__ __forceinline__ float bf2f(u16 h) {
    return __uint_as_float(((u32)h) << 16);
}

// ---------------------------------------------------------------------------
// Split-bf16 MFMA GEMM: C = A @ W^T + bias, fp32 in, fp32 accum.
// A:[M,K] f32, W:[N,K] f32. In-staging decomposition x ~= hi+lo (bf16 RNE),
// C ~= Ah*Wh + Ah*Wl + Al*Wh (rel err ~2^-16).
// Tile 128x128, 4 waves of 64x64, BK=32. LDS [128][40] u16 (2-way max).
// OMODE 0: dense f32 C[m*N+n].  OMODE 1: scatter bf16 hi/lo to [b][h][s][d].
// OMODE 2: scatter f32 to [b][h][s][d].
// ---------------------------------------------------------------------------
template <int OMODE>
__global__ __launch_bounds__(256) void gemm_mfma(const float* __restrict__ A,
                                                 const float* __restrict__ W,
                                                 const float* __restrict__ bias,
                                                 float* __restrict__ Cf,
                                                 u16* __restrict__ Chi,
                                                 u16* __restrict__ Clo,
                                                 int M, int N, int K) {
    __shared__ __align__(16) u16 AhS[128][40];
    __shared__ __align__(16) u16 AlS[128][40];
    __shared__ __align__(16) u16 WhS[128][40];
    __shared__ __align__(16) u16 WlS[128][40];

    const int t    = threadIdx.x;
    const int m0   = blockIdx.y * 128;
    const int n0   = blockIdx.x * 128;
    const int srow = t >> 1;            // 0..127 staging row
    const int sk   = (t & 1) * 16;      // k-half (16 elements)
    const int w    = t >> 6;            // wave 0..3
    const int lane = t & 63;
    const int wr   = w >> 1, wc = w & 1;
    const int fr   = lane & 15;         // fragment row/col
    const int kg   = lane >> 4;         // k-group 0..3

    const float* Abase = A + (size_t)(m0 + srow) * K + sk;
    const float* Wbase = W + (size_t)(n0 + srow) * K + sk;

    float4 pa[4], pw[4];
#pragma unroll
    for (int i = 0; i < 4; ++i) {
        pa[i] = *(const float4*)(Abase + i * 4);
        pw[i] = *(const float4*)(Wbase + i * 4);
    }

    f32x4 acc[4][4] = {};

    for (int kc = 0; kc < K; kc += 32) {
        u32 hA[8], lA[8], hW[8], lW[8];
#pragma unroll
        for (int i = 0; i < 4; ++i) {
            float xs[4] = {pa[i].x, pa[i].y, pa[i].z, pa[i].w};
            float ys[4] = {pw[i].x, pw[i].y, pw[i].z, pw[i].w};
#pragma unroll
            for (int j = 0; j < 2; ++j) {
                u16 a0 = f2bf(xs[2 * j]), a1 = f2bf(xs[2 * j + 1]);
                hA[i * 2 + j] = (u32)a0 | ((u32)a1 << 16);
                lA[i * 2 + j] = (u32)f2bf(xs[2 * j] - bf2f(a0)) |
                                ((u32)f2bf(xs[2 * j + 1] - bf2f(a1)) << 16);
                u16 w0 = f2bf(ys[2 * j]), w1 = f2bf(ys[2 * j + 1]);
                hW[i * 2 + j] = (u32)w0 | ((u32)w1 << 16);
                lW[i * 2 + j] = (u32)f2bf(ys[2 * j] - bf2f(w0)) |
                                ((u32)f2bf(ys[2 * j + 1] - bf2f(w1)) << 16);
            }
        }
        *(uint4*)&AhS[srow][sk]     = make_uint4(hA[0], hA[1], hA[2], hA[3]);
        *(uint4*)&AhS[srow][sk + 8] = make_uint4(hA[4], hA[5], hA[6], hA[7]);
        *(uint4*)&AlS[srow][sk]     = make_uint4(lA[0], lA[1], lA[2], lA[3]);
        *(uint4*)&AlS[srow][sk + 8] = make_uint4(lA[4], lA[5], lA[6], lA[7]);
        *(uint4*)&WhS[srow][sk]     = make_uint4(hW[0], hW[1], hW[2], hW[3]);
        *(uint4*)&WhS[srow][sk + 8] = make_uint4(hW[4], hW[5], hW[6], hW[7]);
        *(uint4*)&WlS[srow][sk]     = make_uint4(lW[0], lW[1], lW[2], lW[3]);
        *(uint4*)&WlS[srow][sk + 8] = make_uint4(lW[4], lW[5], lW[6], lW[7]);
        __syncthreads();

        if (kc + 32 < K) {
#pragma unroll
            for (int i = 0; i < 4; ++i) {
                pa[i] = *(const float4*)(Abase + kc + 32 + i * 4);
                pw[i] = *(const float4*)(Wbase + kc + 32 + i * 4);
            }
        }

        bf16x8 fah[4], fal[4], fwh[4], fwl[4];
#pragma unroll
        for (int mt = 0; mt < 4; ++mt) {
            fah[mt] = *(const bf16x8*)&AhS[wr * 64 + mt * 16 + fr][kg * 8];
            fal[mt] = *(const bf16x8*)&AlS[wr * 64 + mt * 16 + fr][kg * 8];
        }
#pragma unroll
        for (int nt = 0; nt < 4; ++nt) {
            fwh[nt] = *(const bf16x8*)&WhS[wc * 64 + nt * 16 + fr][kg * 8];
            fwl[nt] = *(const bf16x8*)&WlS[wc * 64 + nt * 16 + fr][kg * 8];
        }
#pragma unroll
        for (int mt = 0; mt < 4; ++mt)
#pragma unroll
            for (int nt = 0; nt < 4; ++nt) {
                acc[mt][nt] = __builtin_amdgcn_mfma_f32_16x16x32_bf16(
                    fah[mt], fwh[nt], acc[mt][nt], 0, 0, 0);
                acc[mt][nt] = __builtin_amdgcn_mfma_f32_16x16x32_bf16(
                    fah[mt], fwl[nt], acc[mt][nt], 0, 0, 0);
                acc[mt][nt] = __builtin_amdgcn_mfma_f32_16x16x32_bf16(
                    fal[mt], fwh[nt], acc[mt][nt], 0, 0, 0);
            }
        __syncthreads();
    }

#pragma unroll
    for (int nt = 0; nt < 4; ++nt) {
        const int n  = n0 + wc * 64 + nt * 16 + fr;
        const float bn = bias[n];
#pragma unroll
        for (int mt = 0; mt < 4; ++mt) {
#pragma unroll
            for (int r = 0; r < 4; ++r) {
                const int m = m0 + wr * 64 + mt * 16 + kg * 4 + r;
                const float v = acc[mt][nt][r] + bn;
                if (OMODE == 0) {
                    Cf[(size_t)m * N + n] = v;
                } else {
                    const int b = m >> 10, s = m & (S_ - 1);
                    const int h = n >> 6, d = n & 63;
                    const size_t off = (((size_t)b * H_ + h) * S_ + s) * DK_ + d;
                    if (OMODE == 2) {
                        Cf[off] = v;
                    } else {
                        const u16 hh = f2bf(v);
                        Chi[off] = hh;
                        Clo[off] = f2bf(v - bf2f(hh));
                    }
                }
            }
        }
    }
}

// ---------------------------------------------------------------------------
// scores = Qh @ Kh^T per (b,h) from pre-split bf16 hi/lo, fp32 out to
// attn region [h*B+b][i][j]. Same tile structure, K=64 (2 steps of BK=32).
// Grid (8 j-tiles, 8 i-tiles, 64 bh).
// ---------------------------------------------------------------------------
__global__ __launch_bounds__(256) void scores_mfma(const u16* __restrict__ Qhi,
                                                   const u16* __restrict__ Qlo,
                                                   const u16* __restrict__ Khi,
                                                   const u16* __restrict__ Klo,
                                                   float* __restrict__ Sc) {
    const int bh = blockIdx.z;
    const int b = bh >> 4, h = bh & 15;
    const u16* Qh_g = Qhi + (size_t)bh * S_ * DK_;
    const u16* Ql_g = Qlo + (size_t)bh * S_ * DK_;
    const u16* Kh_g = Khi + (size_t)bh * S_ * DK_;
    const u16* Kl_g = Klo + (size_t)bh * S_ * DK_;
    float* C = Sc + (size_t)(h * B_ + b) * S_ * S_;

    __shared__ __align__(16) u16 AhS[128][40];
    __shared__ __align__(16) u16 AlS[128][40];
    __shared__ __align__(16) u16 WhS[128][40];
    __shared__ __align__(16) u16 WlS[128][40];

    const int t    = threadIdx.x;
    const int m0   = blockIdx.y * 128;
    const int n0   = blockIdx.x * 128;
    const int srow = t >> 1;
    const int sk   = (t & 1) * 16;
    const int w    = t >> 6;
    const int lane = t & 63;
    const int wr   = w >> 1, wc = w & 1;
    const int fr   = lane & 15;
    const int kg   = lane >> 4;

    f32x4 acc[4][4] = {};

    for (int kc = 0; kc < DK_; kc += 32) {
        {
            const size_t qa = (size_t)(m0 + srow) * DK_ + kc + sk;
            const size_t ka = (size_t)(n0 + srow) * DK_ + kc + sk;
            uint4 q0 = *(const uint4*)(Qh_g + qa);
            uint4 q1 = *(const uint4*)(Qh_g + qa + 8);
            uint4 q2 = *(const uint4*)(Ql_g + qa);
            uint4 q3 = *(const uint4*)(Ql_g + qa + 8);
            uint4 k0 = *(const uint4*)(Kh_g + ka);
            uint4 k1 = *(const uint4*)(Kh_g + ka + 8);
            uint4 k2 = *(const uint4*)(Kl_g + ka);
            uint4 k3 = *(const uint4*)(Kl_g + ka + 8);
            *(uint4*)&AhS[srow][sk]     = q0;
            *(uint4*)&AhS[srow][sk + 8] = q1;
            *(uint4*)&AlS[srow][sk]     = q2;
            *(uint4*)&AlS[srow][sk + 8] = q3;
            *(uint4*)&WhS[srow][sk]     = k0;
            *(uint4*)&WhS[srow][sk + 8] = k1;
            *(uint4*)&WlS[srow][sk]     = k2;
            *(uint4*)&WlS[srow][sk + 8] = k3;
        }
        __syncthreads();

        bf16x8 fah[4], fal[4], fwh[4], fwl[4];
#pragma unroll
        for (int mt = 0; mt < 4; ++mt) {
            fah[mt] = *(const bf16x8*)&AhS[wr * 64 + mt * 16 + fr][kg * 8];
            fal[mt] = *(const bf16x8*)&AlS[wr * 64 + mt * 16 + fr][kg * 8];
        }
#pragma unroll
        for (int nt = 0; nt < 4; ++nt) {
            fwh[nt] = *(const bf16x8*)&WhS[wc * 64 + nt * 16 + fr][kg * 8];
            fwl[nt] = *(const bf16x8*)&WlS[wc * 64 + nt * 16 + fr][kg * 8];
        }
#pragma unroll
        for (int mt = 0; mt < 4; ++mt)
#pragma unroll
            for (int nt = 0; nt < 4; ++nt) {
                acc[mt][nt] = __builtin_amdgcn_mfma_f32_16x16x32_bf16(
                    fah[mt], fwh[nt], acc[mt][nt], 0, 0, 0);
                acc[mt][nt] = __builtin_amdgcn_mfma_f32_16x16x32_bf16(
                    fah[mt], fwl[nt], acc[mt][nt], 0, 0, 0);
                acc[mt][nt] = __builtin_amdgcn_mfma_f32_16x16x32_bf16(
                    fal[mt], fwh[nt], acc[mt][nt], 0, 0, 0);
            }
        __syncthreads();
    }

#pragma unroll
    for (int nt = 0; nt < 4; ++nt) {
        const int j = n0 + wc * 64 + nt * 16 + fr;
#pragma unroll
        for (int mt = 0; mt < 4; ++mt) {
#pragma unroll
            for (int r = 0; r < 4; ++r) {
                const int i = m0 + wr * 64 + mt * 16 + kg * 4 + r;
                C[(size_t)i * S_ + j] = acc[mt][nt][r];
            }
        }
    }
}

// ---------------------------------------------------------------------------
// In-place row softmax over the attn region. One block per row of 1024.
// Replay-safe: scores_mfma regenerates raw scores on every replay.
// ---------------------------------------------------------------------------
__global__ __launch_bounds__(256) void softmax_rows(float* __restrict__ attn) {
    const size_t row = blockIdx.x;
    float* p = attn + row * S_;
    const int t = threadIdx.x;

    float4 v = ((const float4*)p)[t];
    float mx = fmaxf(fmaxf(v.x, v.y), fmaxf(v.z, v.w));
#pragma unroll
    for (int o = 32; o > 0; o >>= 1) mx = fmaxf(mx, __shfl_xor(mx, o, 64));

    __shared__ float red[8];
    const int w = t >> 6;
    if ((t & 63) == 0) red[w] = mx;
    __syncthreads();
    mx = fmaxf(fmaxf(red[0], red[1]), fmaxf(red[2], red[3]));

    float4 e;
    e.x = __expf(v.x - mx);
    e.y = __expf(v.y - mx);
    e.z = __expf(v.z - mx);
    e.w = __expf(v.w - mx);
    float s = e.x + e.y + e.z + e.w;
#pragma unroll
    for (int o = 32; o > 0; o >>= 1) s += __shfl_xor(s, o, 64);
    if ((t & 63) == 0) red[4 + w] = s;
    __syncthreads();
    s = red[4] + red[5] + red[6] + red[7];

    const float inv = 1.0f / s;
    e.x *= inv; e.y *= inv; e.z *= inv; e.w *= inv;
    ((float4*)p)[t] = e;
}

// ---------------------------------------------------------------------------
// ctx = attn @ V per (b,h). 256x64 tile per block, 8x8 micro (cols split
// tn*4 / 32+tn*4). K-chunk 16 with register prefetch. Grid (4, 64).
// Output -> ctx[b][s][h*64+d].
// ---------------------------------------------------------------------------
__global__ __launch_bounds__(256) void attn_pv(const float* __restrict__ attn,
                                               const float* __restrict__ Vh,
                                               float* __restrict__ ctx) {
    const int bh = blockIdx.y;
    const int b = bh >> 4, h = bh & 15;
    const int i0 = blockIdx.x * 256;
    const int t  = threadIdx.x;
    const int tm = t >> 3;
    const int tn = t & 7;
    const int srow = t >> 2;
    const int scg  = (t & 3) * 4;
    const int vrow = t >> 4;
    const int vcg  = (t & 15) * 4;

    __shared__ float As[16][260];
    __shared__ float Vs[16][68];

    const float* abase = attn + ((size_t)(h * B_ + b) * S_ + i0) * S_;
    const float* vbase = Vh + (size_t)bh * S_ * DK_;

    const float* Ar0 = abase + (size_t)(srow)       * S_ + scg;
    const float* Ar1 = abase + (size_t)(srow + 64)  * S_ + scg;
    const float* Ar2 = abase + (size_t)(srow + 128) * S_ + scg;
    const float* Ar3 = abase + (size_t)(srow + 192) * S_ + scg;
    const float* Vr  = vbase + (size_t)vrow * DK_ + vcg;

    float4 pa0 = *(const float4*)Ar0;
    float4 pa1 = *(const float4*)Ar1;
    float4 pa2 = *(const float4*)Ar2;
    float4 pa3 = *(const float4*)Ar3;
    float4 pv  = *(const float4*)Vr;

    float acc[8][8] = {};

    for (int kc = 0; kc < S_; kc += 16) {
        As[scg + 0][srow]       = pa0.x;
        As[scg + 1][srow]       = pa0.y;
        As[scg + 2][srow]       = pa0.z;
        As[scg + 3][srow]       = pa0.w;
        As[scg + 0][srow + 64]  = pa1.x;
        As[scg + 1][srow + 64]  = pa1.y;
        As[scg + 2][srow + 64]  = pa1.z;
        As[scg + 3][srow + 64]  = pa1.w;
        As[scg + 0][srow + 128] = pa2.x;
        As[scg + 1][srow + 128] = pa2.y;
        As[scg + 2][srow + 128] = pa2.z;
        As[scg + 3][srow + 128] = pa2.w;
        As[scg + 0][srow + 192] = pa3.x;
        As[scg + 1][srow + 192] = pa3.y;
        As[scg + 2][srow + 192] = pa3.z;
        As[scg + 3][srow + 192] = pa3.w;
        *(float4*)&Vs[vrow][vcg] = pv;
        __syncthreads();
        if (kc + 16 < S_) {
            pa0 = *(const float4*)(Ar0 + kc + 16);
            pa1 = *(const float4*)(Ar1 + kc + 16);
            pa2 = *(const float4*)(Ar2 + kc + 16);
            pa3 = *(const float4*)(Ar3 + kc + 16);
            pv  = *(const float4*)(Vr + (size_t)(kc + 16) * DK_);
        }
#pragma unroll
        for (int kk = 0; kk < 16; ++kk) {
            float4 a0 = *(const float4*)&As[kk][tm * 8];
            float4 a1 = *(const float4*)&As[kk][tm * 8 + 4];
            float4 v0 = *(const float4*)&Vs[kk][tn * 4];
            float4 v1 = *(const float4*)&Vs[kk][32 + tn * 4];
            float av[8] = {a0.x, a0.y, a0.z, a0.w, a1.x, a1.y, a1.z, a1.w};
            float vv[8] = {v0.x, v0.y, v0.z, v0.w, v1.x, v1.y, v1.z, v1.w};
#pragma unroll
            for (int i = 0; i < 8; ++i)
#pragma unroll
                for (int j = 0; j < 8; ++j) acc[i][j] += av[i] * vv[j];
        }
        __syncthreads();
    }

#pragma unroll
    for (int i = 0; i < 8; ++i) {
        const int m = i0 + tm * 8 + i;
        float* crow = ctx + ((size_t)b * S_ + m) * D_ + h * DK_;
        *(float4*)(crow + tn * 4) =
            make_float4(acc[i][0], acc[i][1], acc[i][2], acc[i][3]);
        *(float4*)(crow + 32 + tn * 4) =
            make_float4(acc[i][4], acc[i][5], acc[i][6], acc[i][7]);
    }
}

// ---------------------------------------------------------------------------
// y = LayerNorm(x + residual_q) * gamma + beta  (one block per row of 1024)
// ---------------------------------------------------------------------------
__global__ __launch_bounds__(256) void ln_kernel(const float* __restrict__ X,
                                                 const float* __restrict__ q,
                                                 const float* __restrict__ gamma,
                                                 const float* __restrict__ beta,
                                                 float* __restrict__ y) {
    const int row = blockIdx.x;
    const int t   = threadIdx.x;
    const size_t base = (size_t)row * D_;

    float4 xv = *(const float4*)(X + base + t * 4);
    float4 qv = *(const float4*)(q + base + t * 4);
    const float x0 = xv.x + qv.x, x1 = xv.y + qv.y;
    const float x2 = xv.z + qv.z, x3 = xv.w + qv.w;

    float sum = x0 + x1 + x2 + x3;
    float sq  = x0 * x0 + x1 * x1 + x2 * x2 + x3 * x3;
#pragma unroll
    for (int o = 32; o > 0; o >>= 1) {
        sum += __shfl_xor(sum, o, 64);
        sq  += __shfl_xor(sq, o, 64);
    }
    __shared__ float red[8];
    const int wv = t >> 6;
    if ((t & 63) == 0) { red[wv] = sum; red[4 + wv] = sq; }
    __syncthreads();
    sum = red[0] + red[1] + red[2] + red[3];
    sq  = red[4] + red[5] + red[6] + red[7];

    const float mu  = sum * (1.0f / 1024.0f);
    const float var = sq * (1.0f / 1024.0f) - mu * mu;
    const float rs  = rsqrtf(var + 1e-5f);

    float4 gv = *(const float4*)(gamma + t * 4);
    float4 bv = *(const float4*)(beta + t * 4);
    float4 o;
    o.x = (x0 - mu) * rs * gv.x + bv.x;
    o.y = (x1 - mu) * rs * gv.y + bv.y;
    o.z = (x2 - mu) * rs * gv.z + bv.z;
    o.w = (x3 - mu) * rs * gv.w + bv.w;
    *(float4*)(y + base + t * 4) = o;
}

extern "C" void kernel_launch(void* const* d_in, const int* in_sizes, int n_in,
                              void* d_out, int out_size, void* d_ws, size_t ws_size,
                              hipStream_t stream) {
    const float* q    = (const float*)d_in[0];
    const float* k    = (const float*)d_in[1];
    const float* v    = (const float*)d_in[2];
    const float* Wq   = (const float*)d_in[3];
    const float* bq   = (const float*)d_in[4];
    const float* Wk   = (const float*)d_in[5];
    const float* bk   = (const float*)d_in[6];
    const float* Wv   = (const float*)d_in[7];
    const float* bv   = (const float*)d_in[8];
    const float* Wfc  = (const float*)d_in[9];
    const float* bfc  = (const float*)d_in[10];
    const float* gamma= (const float*)d_in[11];
    const float* beta = (const float*)d_in[12];

    float* y_out    = (float*)d_out;
    float* attn_out = (float*)d_out + (size_t)B_ * S_ * D_;   // fp32 outputs

    // Workspace 48 MiB, float units:
    //  [0,        4194304)  Vh fp32           [b][h][s][64]
    //  [4194304,  6291456)  Qhi bf16 (4M u16) [b][h][s][64]
    //  [6291456,  8388608)  Qlo bf16
    //  [8388608, 10485760)  Khi bf16
    //  [10485760,12582912)  Klo bf16
    //  ctx  fp32 reuses Qhi+Qlo region after scores; xbuf reuses Khi+Klo.
    float* ws  = (float*)d_ws;
    float* Vh  = ws;
    u16*  Qhi  = (u16*)(ws + 4194304);
    u16*  Qlo  = (u16*)(ws + 6291456);
    u16*  Khi  = (u16*)(ws + 8388608);
    u16*  Klo  = (u16*)(ws + 10485760);
    float* ctx  = ws + 4194304;       // 16 MiB (Q splits dead after scores)
    float* xbuf = ws + 8388608;       // 16 MiB (K splits dead after scores)

    const dim3 gg(8, 32), bb(256);    // 128x128 tiles: N/128=8, M/128=32
    gemm_mfma<1><<<gg, bb, 0, stream>>>(q, Wq, bq, nullptr, Qhi, Qlo, 4096, 1024, 1024);
    gemm_mfma<1><<<gg, bb, 0, stream>>>(k, Wk, bk, nullptr, Khi, Klo, 4096, 1024, 1024);
    gemm_mfma<2><<<gg, bb, 0, stream>>>(v, Wv, bv, Vh, nullptr, nullptr, 4096, 1024, 1024);

    scores_mfma<<<dim3(8, 8, 64), bb, 0, stream>>>(Qhi, Qlo, Khi, Klo, attn_out);
    softmax_rows<<<dim3(B_ * H_ * S_), bb, 0, stream>>>(attn_out);

    attn_pv<<<dim3(4, 64), bb, 0, stream>>>(attn_out, Vh, ctx);

    gemm_mfma<0><<<gg, bb, 0, stream>>>(ctx, Wfc, bfc, xbuf, nullptr, nullptr, 4096, 1024, 1024);
    ln_kernel<<<4096, 256, 0, stream>>>(xbuf, q, gamma, beta, y_out);
}

// Round 5
// 694.289 us; speedup vs baseline: 3.9544x; 1.1664x over previous
//
#include <hip/hip_runtime.h>
#include <stdint.h>

#define B_ 4
#define S_ 1024
#define D_ 1024
#define H_ 16
#define DK_ 64

typedef unsigned short u16;
typedef unsigned int   u32;
typedef short bf16x8 __attribute__((ext_vector_type(8)));
typedef float f32x4  __attribute__((ext_vector_type(4)));

__device__ __forceinline__ u16 f2bf(float x) {            // RNE fp32 -> bf16
    u32 u = __float_as_uint(x);
    return (u16)((u + 0x7fffu + ((u >> 16) & 1u)) >> 16);
}
__device__ __forceinline__ float bf2f(u16 h) {
    return __uint_as_float(((u32)h) << 16);
}

// ---------------------------------------------------------------------------
// Split-bf16 MFMA GEMM: C = A @ W^T + bias, fp32 accum.
// AMODE 0: A fp32, split in staging (3 MFMA terms: AhWh+AhWl+AlWh).
// AMODE 1: A bf16 u16 (exact), 2 MFMA terms (AhWh+AhWl).
// OMODE 0: dense f32 C[m*N+n].
// OMODE 1: scatter bf16 hi/lo to [b][h][s][d] (m=b*S+s, n=h*64+d).
// OMODE 2: scatter bf16 single TRANSPOSED to [b][h][d][s].
// Tile 128x128, 4 waves of 64x64, BK=32. LDS [128][40] u16 (2-way max).
// ---------------------------------------------------------------------------
template <int OMODE, int AMODE>
__global__ __launch_bounds__(256) void gemm_mfma(const void* __restrict__ Ain,
                                                 const float* __restrict__ W,
                                                 const float* __restrict__ bias,
                                                 float* __restrict__ Cf,
                                                 u16* __restrict__ Chi,
                                                 u16* __restrict__ Clo,
                                                 int M, int N, int K) {
    __shared__ __align__(16) u16 AhS[128][40];
    __shared__ __align__(16) u16 AlS[128][40];
    __shared__ __align__(16) u16 WhS[128][40];
    __shared__ __align__(16) u16 WlS[128][40];

    const int t    = threadIdx.x;
    const int m0   = blockIdx.y * 128;
    const int n0   = blockIdx.x * 128;
    const int srow = t >> 1;            // 0..127 staging row
    const int sk   = (t & 1) * 16;      // k-half (16 elements)
    const int w    = t >> 6;            // wave 0..3
    const int lane = t & 63;
    const int wr   = w >> 1, wc = w & 1;
    const int fr   = lane & 15;         // fragment row/col
    const int kg   = lane >> 4;         // k-group 0..3

    const float* Af = (const float*)Ain;
    const u16*   Ab = (const u16*)Ain;

    const float* Wbase = W + (size_t)(n0 + srow) * K + sk;
    float4 pw[4];
#pragma unroll
    for (int i = 0; i < 4; ++i) pw[i] = *(const float4*)(Wbase + i * 4);

    float4 pa[4];
    uint4  ua[2];
    if constexpr (AMODE == 0) {
        const float* Abase = Af + (size_t)(m0 + srow) * K + sk;
#pragma unroll
        for (int i = 0; i < 4; ++i) pa[i] = *(const float4*)(Abase + i * 4);
    } else {
        const u16* Abase = Ab + (size_t)(m0 + srow) * K + sk;
        ua[0] = *(const uint4*)(Abase);
        ua[1] = *(const uint4*)(Abase + 8);
    }

    f32x4 acc[4][4] = {};

    for (int kc = 0; kc < K; kc += 32) {
        if constexpr (AMODE == 0) {
            u32 hA[8], lA[8];
#pragma unroll
            for (int i = 0; i < 4; ++i) {
                float xs[4] = {pa[i].x, pa[i].y, pa[i].z, pa[i].w};
#pragma unroll
                for (int j = 0; j < 2; ++j) {
                    u16 a0 = f2bf(xs[2 * j]), a1 = f2bf(xs[2 * j + 1]);
                    hA[i * 2 + j] = (u32)a0 | ((u32)a1 << 16);
                    lA[i * 2 + j] = (u32)f2bf(xs[2 * j] - bf2f(a0)) |
                                    ((u32)f2bf(xs[2 * j + 1] - bf2f(a1)) << 16);
                }
            }
            *(uint4*)&AhS[srow][sk]     = make_uint4(hA[0], hA[1], hA[2], hA[3]);
            *(uint4*)&AhS[srow][sk + 8] = make_uint4(hA[4], hA[5], hA[6], hA[7]);
            *(uint4*)&AlS[srow][sk]     = make_uint4(lA[0], lA[1], lA[2], lA[3]);
            *(uint4*)&AlS[srow][sk + 8] = make_uint4(lA[4], lA[5], lA[6], lA[7]);
        } else {
            *(uint4*)&AhS[srow][sk]     = ua[0];
            *(uint4*)&AhS[srow][sk + 8] = ua[1];
        }
        {
            u32 hW[8], lW[8];
#pragma unroll
            for (int i = 0; i < 4; ++i) {
                float ys[4] = {pw[i].x, pw[i].y, pw[i].z, pw[i].w};
#pragma unroll
                for (int j = 0; j < 2; ++j) {
                    u16 w0 = f2bf(ys[2 * j]), w1 = f2bf(ys[2 * j + 1]);
                    hW[i * 2 + j] = (u32)w0 | ((u32)w1 << 16);
                    lW[i * 2 + j] = (u32)f2bf(ys[2 * j] - bf2f(w0)) |
                                    ((u32)f2bf(ys[2 * j + 1] - bf2f(w1)) << 16);
                }
            }
            *(uint4*)&WhS[srow][sk]     = make_uint4(hW[0], hW[1], hW[2], hW[3]);
            *(uint4*)&WhS[srow][sk + 8] = make_uint4(hW[4], hW[5], hW[6], hW[7]);
            *(uint4*)&WlS[srow][sk]     = make_uint4(lW[0], lW[1], lW[2], lW[3]);
            *(uint4*)&WlS[srow][sk + 8] = make_uint4(lW[4], lW[5], lW[6], lW[7]);
        }
        __syncthreads();

        if (kc + 32 < K) {
            if constexpr (AMODE == 0) {
                const float* Abase = Af + (size_t)(m0 + srow) * K + sk;
#pragma unroll
                for (int i = 0; i < 4; ++i)
                    pa[i] = *(const float4*)(Abase + kc + 32 + i * 4);
            } else {
                const u16* Abase = Ab + (size_t)(m0 + srow) * K + sk;
                ua[0] = *(const uint4*)(Abase + kc + 32);
                ua[1] = *(const uint4*)(Abase + kc + 32 + 8);
            }
#pragma unroll
            for (int i = 0; i < 4; ++i)
                pw[i] = *(const float4*)(Wbase + kc + 32 + i * 4);
        }

        bf16x8 fah[4], fal[4], fwh[4], fwl[4];
#pragma unroll
        for (int mt = 0; mt < 4; ++mt) {
            fah[mt] = *(const bf16x8*)&AhS[wr * 64 + mt * 16 + fr][kg * 8];
            if constexpr (AMODE == 0)
                fal[mt] = *(const bf16x8*)&AlS[wr * 64 + mt * 16 + fr][kg * 8];
        }
#pragma unroll
        for (int nt = 0; nt < 4; ++nt) {
            fwh[nt] = *(const bf16x8*)&WhS[wc * 64 + nt * 16 + fr][kg * 8];
            fwl[nt] = *(const bf16x8*)&WlS[wc * 64 + nt * 16 + fr][kg * 8];
        }
#pragma unroll
        for (int mt = 0; mt < 4; ++mt)
#pragma unroll
            for (int nt = 0; nt < 4; ++nt) {
                acc[mt][nt] = __builtin_amdgcn_mfma_f32_16x16x32_bf16(
                    fah[mt], fwh[nt], acc[mt][nt], 0, 0, 0);
                acc[mt][nt] = __builtin_amdgcn_mfma_f32_16x16x32_bf16(
                    fah[mt], fwl[nt], acc[mt][nt], 0, 0, 0);
                if constexpr (AMODE == 0)
                    acc[mt][nt] = __builtin_amdgcn_mfma_f32_16x16x32_bf16(
                        fal[mt], fwh[nt], acc[mt][nt], 0, 0, 0);
            }
        __syncthreads();
    }

#pragma unroll
    for (int nt = 0; nt < 4; ++nt) {
        const int n  = n0 + wc * 64 + nt * 16 + fr;
        const float bn = bias[n];
#pragma unroll
        for (int mt = 0; mt < 4; ++mt) {
#pragma unroll
            for (int r = 0; r < 4; ++r) {
                const int m = m0 + wr * 64 + mt * 16 + kg * 4 + r;
                const float v = acc[mt][nt][r] + bn;
                if (OMODE == 0) {
                    Cf[(size_t)m * N + n] = v;
                } else {
                    const int b = m >> 10, s = m & (S_ - 1);
                    const int h = n >> 6, d = n & 63;
                    if (OMODE == 1) {
                        const size_t off = (((size_t)b * H_ + h) * S_ + s) * DK_ + d;
                        const u16 hh = f2bf(v);
                        Chi[off] = hh;
                        Clo[off] = f2bf(v - bf2f(hh));
                    } else {   // OMODE 2: transposed bf16 [b][h][d][s]
                        Chi[(((size_t)b * H_ + h) * DK_ + d) * S_ + s] = f2bf(v);
                    }
                }
            }
        }
    }
}

// ---------------------------------------------------------------------------
// Fused attention: per block = 32 q-rows x one (b,h).
// Phase 1: QK^T (split-bf16, 3-term) over 8 chunks of 128 K-rows; full
//          1024-col score row kept in registers (acc[2][16] f32x4 / lane).
// Phase 2: full-row softmax in-register (shfl within 16-lane col groups +
//          LDS across the 4 waves); write fp32 attn once.
// Phase 3: PV with single-bf16 MFMA: P -> LDS (XOR-swizzled) per chunk,
//          V^T staged from global bf16 [b][h][d][s]; ctx out as bf16.
// Waves partition cols: wave w owns cols {ch*128 + w*32 .. +32} per chunk,
// and d = w*16..+16 of the output. XOR swizzle byte^=((row&7)<<4) kills the
// stride-256B 16-way bank conflicts on K/P/VT fragment reads.
// ---------------------------------------------------------------------------
__global__ __launch_bounds__(256) void fused_attn(const u16* __restrict__ Qhi,
                                                  const u16* __restrict__ Qlo,
                                                  const u16* __restrict__ Khi,
                                                  const u16* __restrict__ Klo,
                                                  const u16* __restrict__ VT,
                                                  float* __restrict__ attn,
                                                  u16* __restrict__ ctx) {
    const int bh = blockIdx.y;
    const int b  = bh >> 4, h = bh & 15;
    const int i0 = blockIdx.x * 32;
    const int t  = threadIdx.x;
    const int w  = t >> 6;
    const int lane = t & 63;
    const int c  = lane & 15;           // fragment col/row low
    const int q  = lane >> 4;           // k-group / row-quad

    __shared__ __align__(16) u16 smem[2 * 128 * 64];   // 32 KB, phase-unioned
    u16* KhiL = smem;                   // ph1: [128][64] swizzled
    u16* KloL = smem + 128 * 64;
    u16* Pl   = smem;                   // ph3: [32][128] swizzled (8 KB)
    u16* VTl  = smem + 32 * 128;        // ph3: [64][128] swizzled (16 KB)
    __shared__ float redS[4][32];

    // Q fragments (rows i0..i0+31, k=0..63) hi/lo, loaded once.
    bf16x8 qh[2][2], ql[2][2];
#pragma unroll
    for (int mt = 0; mt < 2; ++mt)
#pragma unroll
        for (int kf = 0; kf < 2; ++kf) {
            const size_t off = ((size_t)bh * S_ + i0 + mt * 16 + c) * DK_ + kf * 32 + q * 8;
            qh[mt][kf] = *(const bf16x8*)(Qhi + off);
            ql[mt][kf] = *(const bf16x8*)(Qlo + off);
        }

    f32x4 acc[2][16] = {};

    // ---- Phase 1: QK^T ----
#pragma unroll
    for (int ch = 0; ch < 8; ++ch) {
        __syncthreads();
#pragma unroll
        for (int u = 0; u < 4; ++u) {
            const int unit = t * 4 + u;             // 0..1023 (16B units)
            const int j = unit >> 3, k16 = unit & 7;
            const int dstb = j * 128 + ((k16 * 16) ^ ((j & 7) << 4));
            const size_t src = ((size_t)bh * S_ + ch * 128 + j) * DK_ + k16 * 8;
            *(uint4*)((char*)KhiL + dstb) = *(const uint4*)(Khi + src);
            *(uint4*)((char*)KloL + dstb) = *(const uint4*)(Klo + src);
        }
        __syncthreads();
#pragma unroll
        for (int ct = 0; ct < 2; ++ct) {
            const int j = w * 32 + ct * 16 + c;     // K-row within chunk
#pragma unroll
            for (int kf = 0; kf < 2; ++kf) {
                const int byt = j * 128 + ((kf * 64 + q * 16) ^ ((j & 7) << 4));
                bf16x8 kh = *(const bf16x8*)((char*)KhiL + byt);
                bf16x8 kl = *(const bf16x8*)((char*)KloL + byt);
#pragma unroll
                for (int mt = 0; mt < 2; ++mt) {
                    acc[mt][ch * 2 + ct] = __builtin_amdgcn_mfma_f32_16x16x32_bf16(
                        qh[mt][kf], kh, acc[mt][ch * 2 + ct], 0, 0, 0);
                    acc[mt][ch * 2 + ct] = __builtin_amdgcn_mfma_f32_16x16x32_bf16(
                        ql[mt][kf], kh, acc[mt][ch * 2 + ct], 0, 0, 0);
                    acc[mt][ch * 2 + ct] = __builtin_amdgcn_mfma_f32_16x16x32_bf16(
                        qh[mt][kf], kl, acc[mt][ch * 2 + ct], 0, 0, 0);
                }
            }
        }
    }

    // ---- Phase 2: softmax over full 1024-col rows ----
    float mx[2][4];
#pragma unroll
    for (int mt = 0; mt < 2; ++mt)
#pragma unroll
        for (int r = 0; r < 4; ++r) {
            float m = -1e30f;
#pragma unroll
            for (int ci = 0; ci < 16; ++ci) m = fmaxf(m, acc[mt][ci][r]);
#pragma unroll
            for (int o = 1; o < 16; o <<= 1) m = fmaxf(m, __shfl_xor(m, o, 64));
            mx[mt][r] = m;
        }
    if (c == 0) {
#pragma unroll
        for (int mt = 0; mt < 2; ++mt)
#pragma unroll
            for (int r = 0; r < 4; ++r) redS[w][mt * 16 + q * 4 + r] = mx[mt][r];
    }
    __syncthreads();
#pragma unroll
    for (int mt = 0; mt < 2; ++mt)
#pragma unroll
        for (int r = 0; r < 4; ++r) {
            const int row = mt * 16 + q * 4 + r;
            mx[mt][r] = fmaxf(fmaxf(redS[0][row], redS[1][row]),
                              fmaxf(redS[2][row], redS[3][row]));
        }
    float sm[2][4] = {};
#pragma unroll
    for (int mt = 0; mt < 2; ++mt)
#pragma unroll
        for (int ci = 0; ci < 16; ++ci)
#pragma unroll
            for (int r = 0; r < 4; ++r) {
                const float e = __expf(acc[mt][ci][r] - mx[mt][r]);
                acc[mt][ci][r] = e;
                sm[mt][r] += e;
            }
#pragma unroll
    for (int mt = 0; mt < 2; ++mt)
#pragma unroll
        for (int r = 0; r < 4; ++r)
#pragma unroll
            for (int o = 1; o < 16; o <<= 1) sm[mt][r] += __shfl_xor(sm[mt][r], o, 64);
    __syncthreads();                    // round-1 reads done before overwrite
    if (c == 0) {
#pragma unroll
        for (int mt = 0; mt < 2; ++mt)
#pragma unroll
            for (int r = 0; r < 4; ++r) redS[w][mt * 16 + q * 4 + r] = sm[mt][r];
    }
    __syncthreads();
    float inv[2][4];
#pragma unroll
    for (int mt = 0; mt < 2; ++mt)
#pragma unroll
        for (int r = 0; r < 4; ++r) {
            const int row = mt * 16 + q * 4 + r;
            inv[mt][r] = 1.0f / (redS[0][row] + redS[1][row] + redS[2][row] + redS[3][row]);
        }
    // scale + write attn (fp32, final probabilities)
    float* dst = attn + ((size_t)(h * B_ + b) * S_ + i0) * S_;
#pragma unroll
    for (int mt = 0; mt < 2; ++mt)
#pragma unroll
        for (int ci = 0; ci < 16; ++ci)
#pragma unroll
            for (int r = 0; r < 4; ++r) {
                const float p = acc[mt][ci][r] * inv[mt][r];
                acc[mt][ci][r] = p;
                const int row = mt * 16 + q * 4 + r;
                const int col = (ci >> 1) * 128 + w * 32 + (ci & 1) * 16 + c;
                dst[(size_t)row * S_ + col] = p;
            }

    // ---- Phase 3: ctx = P @ V (single-bf16 MFMA) ----
    f32x4 c2[2] = {};
#pragma unroll
    for (int ch = 0; ch < 8; ++ch) {
        __syncthreads();
        // P slice for this chunk -> LDS (swizzled)
#pragma unroll
        for (int mt = 0; mt < 2; ++mt)
#pragma unroll
            for (int ct = 0; ct < 2; ++ct)
#pragma unroll
                for (int r = 0; r < 4; ++r) {
                    const int row = mt * 16 + q * 4 + r;
                    const int col = w * 32 + ct * 16 + c;
                    const int byt = row * 256 + ((col * 2) ^ ((row & 7) << 4));
                    *(u16*)((char*)Pl + byt) = f2bf(acc[mt][ch * 2 + ct][r]);
                }
        // V^T chunk -> LDS (swizzled): [64 d][128 s]
#pragma unroll
        for (int u = 0; u < 4; ++u) {
            const int unit = t * 4 + u;             // 0..1023
            const int d = unit >> 4, s16 = unit & 15;
            const int byt = d * 256 + ((s16 * 16) ^ ((d & 7) << 4));
            *(uint4*)((char*)VTl + byt) =
                *(const uint4*)(VT + ((size_t)bh * DK_ + d) * S_ + ch * 128 + s16 * 8);
        }
        __syncthreads();
#pragma unroll
        for (int kf = 0; kf < 4; ++kf) {
            const int dloc = w * 16 + c;
            const int vb_byt = dloc * 256 + ((kf * 64 + q * 16) ^ ((c & 7) << 4));
            bf16x8 vb = *(const bf16x8*)((char*)VTl + vb_byt);
#pragma unroll
            for (int mt = 0; mt < 2; ++mt) {
                const int pr = mt * 16 + c;
                const int pa_byt = pr * 256 + ((kf * 64 + q * 16) ^ ((c & 7) << 4));
                bf16x8 pa = *(const bf16x8*)((char*)Pl + pa_byt);
                c2[mt] = __builtin_amdgcn_mfma_f32_16x16x32_bf16(pa, vb, c2[mt], 0, 0, 0);
            }
        }
    }
    // ctx out (bf16): [b][s][h*64 + d]
#pragma unroll
    for (int mt = 0; mt < 2; ++mt)
#pragma unroll
        for (int r = 0; r < 4; ++r) {
            const int s = i0 + mt * 16 + q * 4 + r;
            ctx[((size_t)b * S_ + s) * D_ + h * DK_ + w * 16 + c] = f2bf(c2[mt][r]);
        }
}

// ---------------------------------------------------------------------------
// y = LayerNorm(x + residual_q) * gamma + beta  (one block per row of 1024)
// ---------------------------------------------------------------------------
__global__ __launch_bounds__(256) void ln_kernel(const float* __restrict__ X,
                                                 const float* __restrict__ q,
                                                 const float* __restrict__ gamma,
                                                 const float* __restrict__ beta,
                                                 float* __restrict__ y) {
    const int row = blockIdx.x;
    const int t   = threadIdx.x;
    const size_t base = (size_t)row * D_;

    float4 xv = *(const float4*)(X + base + t * 4);
    float4 qv = *(const float4*)(q + base + t * 4);
    const float x0 = xv.x + qv.x, x1 = xv.y + qv.y;
    const float x2 = xv.z + qv.z, x3 = xv.w + qv.w;

    float sum = x0 + x1 + x2 + x3;
    float sq  = x0 * x0 + x1 * x1 + x2 * x2 + x3 * x3;
#pragma unroll
    for (int o = 32; o > 0; o >>= 1) {
        sum += __shfl_xor(sum, o, 64);
        sq  += __shfl_xor(sq, o, 64);
    }
    __shared__ float red[8];
    const int wv = t >> 6;
    if ((t & 63) == 0) { red[wv] = sum; red[4 + wv] = sq; }
    __syncthreads();
    sum = red[0] + red[1] + red[2] + red[3];
    sq  = red[4] + red[5] + red[6] + red[7];

    const float mu  = sum * (1.0f / 1024.0f);
    const float var = sq * (1.0f / 1024.0f) - mu * mu;
    const float rs  = rsqrtf(var + 1e-5f);

    float4 gv = *(const float4*)(gamma + t * 4);
    float4 bv = *(const float4*)(beta + t * 4);
    float4 o;
    o.x = (x0 - mu) * rs * gv.x + bv.x;
    o.y = (x1 - mu) * rs * gv.y + bv.y;
    o.z = (x2 - mu) * rs * gv.z + bv.z;
    o.w = (x3 - mu) * rs * gv.w + bv.w;
    *(float4*)(y + base + t * 4) = o;
}

extern "C" void kernel_launch(void* const* d_in, const int* in_sizes, int n_in,
                              void* d_out, int out_size, void* d_ws, size_t ws_size,
                              hipStream_t stream) {
    const float* q    = (const float*)d_in[0];
    const float* k    = (const float*)d_in[1];
    const float* v    = (const float*)d_in[2];
    const float* Wq   = (const float*)d_in[3];
    const float* bq   = (const float*)d_in[4];
    const float* Wk   = (const float*)d_in[5];
    const float* bk   = (const float*)d_in[6];
    const float* Wv   = (const float*)d_in[7];
    const float* bv   = (const float*)d_in[8];
    const float* Wfc  = (const float*)d_in[9];
    const float* bfc  = (const float*)d_in[10];
    const float* gamma= (const float*)d_in[11];
    const float* beta = (const float*)d_in[12];

    float* y_out    = (float*)d_out;
    float* attn_out = (float*)d_out + (size_t)B_ * S_ * D_;   // fp32 outputs

    // Workspace 48 MiB (float units):
    //  [0,       2097152)  Qhi bf16 [b][h][s][64]
    //  [2097152, 4194304)  Qlo bf16
    //  [4194304, 6291456)  Khi bf16
    //  [6291456, 8388608)  Klo bf16
    //  [8388608,10485760)  VT  bf16 [b][h][d][s]
    //  [10485760,12582912) ctx bf16 [b][s][1024]
    //  xbuf f32 (16 MiB) reuses Qhi+Qlo region after fused_attn.
    float* ws   = (float*)d_ws;
    u16*  Qhi   = (u16*)(ws);
    u16*  Qlo   = (u16*)(ws + 2097152);
    u16*  Khi   = (u16*)(ws + 4194304);
    u16*  Klo   = (u16*)(ws + 6291456);
    u16*  VTb   = (u16*)(ws + 8388608);
    u16*  ctxb  = (u16*)(ws + 10485760);
    float* xbuf = ws;                  // reuse (Q splits dead after fused_attn)

    const dim3 gg(8, 32), bb(256);     // 128x128 tiles
    gemm_mfma<1, 0><<<gg, bb, 0, stream>>>(q, Wq, bq, nullptr, Qhi, Qlo, 4096, 1024, 1024);
    gemm_mfma<1, 0><<<gg, bb, 0, stream>>>(k, Wk, bk, nullptr, Khi, Klo, 4096, 1024, 1024);
    gemm_mfma<2, 0><<<gg, bb, 0, stream>>>(v, Wv, bv, nullptr, VTb, nullptr, 4096, 1024, 1024);

    fused_attn<<<dim3(32, 64), bb, 0, stream>>>(Qhi, Qlo, Khi, Klo, VTb, attn_out, ctxb);

    gemm_mfma<0, 1><<<gg, bb, 0, stream>>>(ctxb, Wfc, bfc, xbuf, nullptr, nullptr, 4096, 1024, 1024);
    ln_kernel<<<4096, 256, 0, stream>>>(xbuf, q, gamma, beta, y_out);
}

// Round 6
// 661.546 us; speedup vs baseline: 4.1501x; 1.0495x over previous
//
#include <hip/hip_runtime.h>
#include <stdint.h>

#define B_ 4
#define S_ 1024
#define D_ 1024
#define H_ 16
#define DK_ 64

typedef unsigned short u16;
typedef unsigned int   u32;
typedef short bf16x8 __attribute__((ext_vector_type(8)));
typedef float f32x4  __attribute__((ext_vector_type(4)));

__device__ __forceinline__ u16 f2bf(float x) {            // RNE fp32 -> bf16
    u32 u = __float_as_uint(x);
    return (u16)((u + 0x7fffu + ((u >> 16) & 1u)) >> 16);
}
__device__ __forceinline__ float bf2f(u16 h) {
    return __uint_as_float(((u32)h) << 16);
}

// ---------------------------------------------------------------------------
// Split-bf16 MFMA GEMM: C = A @ W^T + bias, fp32 accum.
// AMODE 0: A fp32, split in staging (3 MFMA terms). AMODE 1: A bf16 (2 terms).
// OMODE 0: dense f32. OMODE 1: bf16 hi/lo scatter [b][h][s][d].
// OMODE 2: bf16 single transposed scatter [b][h][d][s].
// ---------------------------------------------------------------------------
template <int OMODE, int AMODE>
__global__ __launch_bounds__(256) void gemm_mfma(const void* __restrict__ Ain,
                                                 const float* __restrict__ W,
                                                 const float* __restrict__ bias,
                                                 float* __restrict__ Cf,
                                                 u16* __restrict__ Chi,
                                                 u16* __restrict__ Clo,
                                                 int M, int N, int K) {
    __shared__ __align__(16) u16 AhS[128][40];
    __shared__ __align__(16) u16 AlS[128][40];
    __shared__ __align__(16) u16 WhS[128][40];
    __shared__ __align__(16) u16 WlS[128][40];

    const int t    = threadIdx.x;
    const int m0   = blockIdx.y * 128;
    const int n0   = blockIdx.x * 128;
    const int srow = t >> 1;            // 0..127 staging row
    const int sk   = (t & 1) * 16;      // k-half (16 elements)
    const int w    = t >> 6;            // wave 0..3
    const int lane = t & 63;
    const int wr   = w >> 1, wc = w & 1;
    const int fr   = lane & 15;         // fragment row/col
    const int kg   = lane >> 4;         // k-group 0..3

    const float* Af = (const float*)Ain;
    const u16*   Ab = (const u16*)Ain;

    const float* Wbase = W + (size_t)(n0 + srow) * K + sk;
    float4 pw[4];
#pragma unroll
    for (int i = 0; i < 4; ++i) pw[i] = *(const float4*)(Wbase + i * 4);

    float4 pa[4];
    uint4  ua[2];
    if constexpr (AMODE == 0) {
        const float* Abase = Af + (size_t)(m0 + srow) * K + sk;
#pragma unroll
        for (int i = 0; i < 4; ++i) pa[i] = *(const float4*)(Abase + i * 4);
    } else {
        const u16* Abase = Ab + (size_t)(m0 + srow) * K + sk;
        ua[0] = *(const uint4*)(Abase);
        ua[1] = *(const uint4*)(Abase + 8);
    }

    f32x4 acc[4][4] = {};

    for (int kc = 0; kc < K; kc += 32) {
        if constexpr (AMODE == 0) {
            u32 hA[8], lA[8];
#pragma unroll
            for (int i = 0; i < 4; ++i) {
                float xs[4] = {pa[i].x, pa[i].y, pa[i].z, pa[i].w};
#pragma unroll
                for (int j = 0; j < 2; ++j) {
                    u16 a0 = f2bf(xs[2 * j]), a1 = f2bf(xs[2 * j + 1]);
                    hA[i * 2 + j] = (u32)a0 | ((u32)a1 << 16);
                    lA[i * 2 + j] = (u32)f2bf(xs[2 * j] - bf2f(a0)) |
                                    ((u32)f2bf(xs[2 * j + 1] - bf2f(a1)) << 16);
                }
            }
            *(uint4*)&AhS[srow][sk]     = make_uint4(hA[0], hA[1], hA[2], hA[3]);
            *(uint4*)&AhS[srow][sk + 8] = make_uint4(hA[4], hA[5], hA[6], hA[7]);
            *(uint4*)&AlS[srow][sk]     = make_uint4(lA[0], lA[1], lA[2], lA[3]);
            *(uint4*)&AlS[srow][sk + 8] = make_uint4(lA[4], lA[5], lA[6], lA[7]);
        } else {
            *(uint4*)&AhS[srow][sk]     = ua[0];
            *(uint4*)&AhS[srow][sk + 8] = ua[1];
        }
        {
            u32 hW[8], lW[8];
#pragma unroll
            for (int i = 0; i < 4; ++i) {
                float ys[4] = {pw[i].x, pw[i].y, pw[i].z, pw[i].w};
#pragma unroll
                for (int j = 0; j < 2; ++j) {
                    u16 w0 = f2bf(ys[2 * j]), w1 = f2bf(ys[2 * j + 1]);
                    hW[i * 2 + j] = (u32)w0 | ((u32)w1 << 16);
                    lW[i * 2 + j] = (u32)f2bf(ys[2 * j] - bf2f(w0)) |
                                    ((u32)f2bf(ys[2 * j + 1] - bf2f(w1)) << 16);
                }
            }
            *(uint4*)&WhS[srow][sk]     = make_uint4(hW[0], hW[1], hW[2], hW[3]);
            *(uint4*)&WhS[srow][sk + 8] = make_uint4(hW[4], hW[5], hW[6], hW[7]);
            *(uint4*)&WlS[srow][sk]     = make_uint4(lW[0], lW[1], lW[2], lW[3]);
            *(uint4*)&WlS[srow][sk + 8] = make_uint4(lW[4], lW[5], lW[6], lW[7]);
        }
        __syncthreads();

        if (kc + 32 < K) {
            if constexpr (AMODE == 0) {
                const float* Abase = Af + (size_t)(m0 + srow) * K + sk;
#pragma unroll
                for (int i = 0; i < 4; ++i)
                    pa[i] = *(const float4*)(Abase + kc + 32 + i * 4);
            } else {
                const u16* Abase = Ab + (size_t)(m0 + srow) * K + sk;
                ua[0] = *(const uint4*)(Abase + kc + 32);
                ua[1] = *(const uint4*)(Abase + kc + 32 + 8);
            }
#pragma unroll
            for (int i = 0; i < 4; ++i)
                pw[i] = *(const float4*)(Wbase + kc + 32 + i * 4);
        }

        bf16x8 fah[4], fal[4], fwh[4], fwl[4];
#pragma unroll
        for (int mt = 0; mt < 4; ++mt) {
            fah[mt] = *(const bf16x8*)&AhS[wr * 64 + mt * 16 + fr][kg * 8];
            if constexpr (AMODE == 0)
                fal[mt] = *(const bf16x8*)&AlS[wr * 64 + mt * 16 + fr][kg * 8];
        }
#pragma unroll
        for (int nt = 0; nt < 4; ++nt) {
            fwh[nt] = *(const bf16x8*)&WhS[wc * 64 + nt * 16 + fr][kg * 8];
            fwl[nt] = *(const bf16x8*)&WlS[wc * 64 + nt * 16 + fr][kg * 8];
        }
#pragma unroll
        for (int mt = 0; mt < 4; ++mt)
#pragma unroll
            for (int nt = 0; nt < 4; ++nt) {
                acc[mt][nt] = __builtin_amdgcn_mfma_f32_16x16x32_bf16(
                    fah[mt], fwh[nt], acc[mt][nt], 0, 0, 0);
                acc[mt][nt] = __builtin_amdgcn_mfma_f32_16x16x32_bf16(
                    fah[mt], fwl[nt], acc[mt][nt], 0, 0, 0);
                if constexpr (AMODE == 0)
                    acc[mt][nt] = __builtin_amdgcn_mfma_f32_16x16x32_bf16(
                        fal[mt], fwh[nt], acc[mt][nt], 0, 0, 0);
            }
        __syncthreads();
    }

#pragma unroll
    for (int nt = 0; nt < 4; ++nt) {
        const int n  = n0 + wc * 64 + nt * 16 + fr;
        const float bn = bias[n];
#pragma unroll
        for (int mt = 0; mt < 4; ++mt) {
#pragma unroll
            for (int r = 0; r < 4; ++r) {
                const int m = m0 + wr * 64 + mt * 16 + kg * 4 + r;
                const float v = acc[mt][nt][r] + bn;
                if (OMODE == 0) {
                    Cf[(size_t)m * N + n] = v;
                } else {
                    const int b = m >> 10, s = m & (S_ - 1);
                    const int h = n >> 6, d = n & 63;
                    if (OMODE == 1) {
                        const size_t off = (((size_t)b * H_ + h) * S_ + s) * DK_ + d;
                        const u16 hh = f2bf(v);
                        Chi[off] = hh;
                        Clo[off] = f2bf(v - bf2f(hh));
                    } else {   // OMODE 2: transposed bf16 [b][h][d][s]
                        Chi[(((size_t)b * H_ + h) * DK_ + d) * S_ + s] = f2bf(v);
                    }
                }
            }
        }
    }
}

// ---------------------------------------------------------------------------
// Fused attention v2: block = 32 q-rows x one (b,h); waves partition score
// COLUMNS (wave w owns cols ch*128 + w*32.. per chunk) AND the PV k-dim.
// Phase 1: QK^T 3-term split-bf16, K fragments loaded DIRECTLY from global
//          (k-contiguous 16B/lane; 16 fully-used 64B lines per instr;
//          L2-resident across the 32 blocks per (b,h)) -- no LDS, no barriers.
// Phase 2: full-row softmax (shfl within 16-lane groups + LDS across waves,
//          3 barriers); fp32 attn written once.
// Phase 3: PV k-partitioned per wave: P transpose through 2KB wave-local
//          double-buffered LDS scratch (no barriers, lgkmcnt-ordered);
//          V^T fragments direct from global; one barrier + LDS reduce of
//          the 4 partial ctx tiles. Scratch swizzle keeps <=2-way banks.
// ---------------------------------------------------------------------------
__global__ __launch_bounds__(256, 2) void fused_attn(const u16* __restrict__ Qhi,
                                                     const u16* __restrict__ Qlo,
                                                     const u16* __restrict__ Khi,
                                                     const u16* __restrict__ Klo,
                                                     const u16* __restrict__ VT,
                                                     float* __restrict__ attn,
                                                     u16* __restrict__ ctx) {
    const int bh = blockIdx.y;
    const int b  = bh >> 4, h = bh & 15;
    const int i0 = blockIdx.x * 32;
    const int t  = threadIdx.x;
    const int w  = t >> 6;
    const int lane = t & 63;
    const int c  = lane & 15;           // fragment row/col low
    const int q  = lane >> 4;           // k-group / row-quad

    // pf: per-wave 8KB partial-ctx slices; wave w's P scratch (2x2KB dbuf)
    // lives INSIDE its own pf slice (only overwritten by its own ctx write,
    // which is wave-ordered after its last scratch read).
    __shared__ __align__(16) float pf[4][32][64];   // 32 KB
    __shared__ float redS[4][32];

    // Q fragments (rows i0..i0+31, k=0..63) hi/lo, loaded once.
    bf16x8 qh[2][2], ql[2][2];
#pragma unroll
    for (int mt = 0; mt < 2; ++mt)
#pragma unroll
        for (int kf = 0; kf < 2; ++kf) {
            const size_t off = ((size_t)bh * S_ + i0 + mt * 16 + c) * DK_ + kf * 32 + q * 8;
            qh[mt][kf] = *(const bf16x8*)(Qhi + off);
            ql[mt][kf] = *(const bf16x8*)(Qlo + off);
        }

    const u16* Kh_g = Khi + (size_t)bh * S_ * DK_;
    const u16* Kl_g = Klo + (size_t)bh * S_ * DK_;

    f32x4 acc[2][16] = {};

    // ---- Phase 1: QK^T, direct global K fragments, barrier-free ----
#pragma unroll
    for (int ch = 0; ch < 8; ++ch) {
#pragma unroll
        for (int ct = 0; ct < 2; ++ct) {
            const int j = ch * 128 + w * 32 + ct * 16 + c;     // K row = score col
#pragma unroll
            for (int kf = 0; kf < 2; ++kf) {
                const size_t ko = (size_t)j * DK_ + kf * 32 + q * 8;
                bf16x8 kh = *(const bf16x8*)(Kh_g + ko);
                bf16x8 kl = *(const bf16x8*)(Kl_g + ko);
#pragma unroll
                for (int mt = 0; mt < 2; ++mt) {
                    acc[mt][ch * 2 + ct] = __builtin_amdgcn_mfma_f32_16x16x32_bf16(
                        qh[mt][kf], kh, acc[mt][ch * 2 + ct], 0, 0, 0);
                    acc[mt][ch * 2 + ct] = __builtin_amdgcn_mfma_f32_16x16x32_bf16(
                        ql[mt][kf], kh, acc[mt][ch * 2 + ct], 0, 0, 0);
                    acc[mt][ch * 2 + ct] = __builtin_amdgcn_mfma_f32_16x16x32_bf16(
                        qh[mt][kf], kl, acc[mt][ch * 2 + ct], 0, 0, 0);
                }
            }
        }
    }

    // ---- Phase 2: softmax over full 1024-col rows ----
    float mx[2][4];
#pragma unroll
    for (int mt = 0; mt < 2; ++mt)
#pragma unroll
        for (int r = 0; r < 4; ++r) {
            float m = -1e30f;
#pragma unroll
            for (int ci = 0; ci < 16; ++ci) m = fmaxf(m, acc[mt][ci][r]);
#pragma unroll
            for (int o = 1; o < 16; o <<= 1) m = fmaxf(m, __shfl_xor(m, o, 64));
            mx[mt][r] = m;
        }
    if (c == 0) {
#pragma unroll
        for (int mt = 0; mt < 2; ++mt)
#pragma unroll
            for (int r = 0; r < 4; ++r) redS[w][mt * 16 + q * 4 + r] = mx[mt][r];
    }
    __syncthreads();
#pragma unroll
    for (int mt = 0; mt < 2; ++mt)
#pragma unroll
        for (int r = 0; r < 4; ++r) {
            const int row = mt * 16 + q * 4 + r;
            mx[mt][r] = fmaxf(fmaxf(redS[0][row], redS[1][row]),
                              fmaxf(redS[2][row], redS[3][row]));
        }
    float sm[2][4] = {};
#pragma unroll
    for (int mt = 0; mt < 2; ++mt)
#pragma unroll
        for (int ci = 0; ci < 16; ++ci)
#pragma unroll
            for (int r = 0; r < 4; ++r) {
                const float e = __expf(acc[mt][ci][r] - mx[mt][r]);
                acc[mt][ci][r] = e;
                sm[mt][r] += e;
            }
#pragma unroll
    for (int mt = 0; mt < 2; ++mt)
#pragma unroll
        for (int r = 0; r < 4; ++r)
#pragma unroll
            for (int o = 1; o < 16; o <<= 1) sm[mt][r] += __shfl_xor(sm[mt][r], o, 64);
    __syncthreads();                    // round-1 redS reads done before overwrite
    if (c == 0) {
#pragma unroll
        for (int mt = 0; mt < 2; ++mt)
#pragma unroll
            for (int r = 0; r < 4; ++r) redS[w][mt * 16 + q * 4 + r] = sm[mt][r];
    }
    __syncthreads();
    float inv[2][4];
#pragma unroll
    for (int mt = 0; mt < 2; ++mt)
#pragma unroll
        for (int r = 0; r < 4; ++r) {
            const int row = mt * 16 + q * 4 + r;
            inv[mt][r] = 1.0f / (redS[0][row] + redS[1][row] + redS[2][row] + redS[3][row]);
        }
    // scale in place + single fp32 attn write
    float* dst = attn + ((size_t)(h * B_ + b) * S_ + i0) * S_;
#pragma unroll
    for (int mt = 0; mt < 2; ++mt)
#pragma unroll
        for (int ci = 0; ci < 16; ++ci)
#pragma unroll
            for (int r = 0; r < 4; ++r) {
                const float p = acc[mt][ci][r] * inv[mt][r];
                acc[mt][ci][r] = p;
                const int row = mt * 16 + q * 4 + r;
                const int col = (ci >> 1) * 128 + w * 32 + (ci & 1) * 16 + c;
                dst[(size_t)row * S_ + col] = p;
            }

    // ---- Phase 3: PV, k-partitioned per wave, wave-local P transpose ----
    const u16* VT_g = VT + (size_t)bh * DK_ * S_;
    u16* swb = (u16*)&pf[w][0][0];      // 4 KB of wave's own 8 KB slice
    f32x4 ctxa[2][4] = {};              // [mt][dt] partial over wave's k-slice

#pragma unroll
    for (int ch = 0; ch < 8; ++ch) {
        u16* sw = swb + (ch & 1) * 2048;            // dbuf: 2048 u16 = 4 KB? (2KB each)
        // write wave's 32x32 P block (rows x wave-local cols), swizzled
#pragma unroll
        for (int mt = 0; mt < 2; ++mt)
#pragma unroll
            for (int ctl = 0; ctl < 2; ++ctl)
#pragma unroll
                for (int r = 0; r < 4; ++r) {
                    const int row = mt * 16 + q * 4 + r;
                    const int col = ctl * 16 + c;
                    const int byt = row * 64 + ((col * 2) ^ (((row >> 1) & 3) << 4));
                    *(u16*)((char*)sw + byt) = f2bf(acc[mt][ch * 2 + ctl][r]);
                }
        // read A-fragments (row = mt*16 + c, k = q*8..+8), wave-ordered
        bf16x8 pa[2];
#pragma unroll
        for (int mt = 0; mt < 2; ++mt) {
            const int row = mt * 16 + c;
            const int byt = row * 64 + ((q * 16) ^ (((row >> 1) & 3) << 4));
            pa[mt] = *(const bf16x8*)((char*)sw + byt);
        }
        // V^T fragments direct from global; k-slice = cols ch*128 + w*32 ..+32
#pragma unroll
        for (int dt = 0; dt < 4; ++dt) {
            const int d = dt * 16 + c;
            bf16x8 vb = *(const bf16x8*)(VT_g + (size_t)d * S_ + ch * 128 + w * 32 + q * 8);
#pragma unroll
            for (int mt = 0; mt < 2; ++mt)
                ctxa[mt][dt] = __builtin_amdgcn_mfma_f32_16x16x32_bf16(
                    pa[mt], vb, ctxa[mt][dt], 0, 0, 0);
        }
    }

    // partial ctx -> LDS (each wave writes only its own pf slice)
#pragma unroll
    for (int mt = 0; mt < 2; ++mt)
#pragma unroll
        for (int dt = 0; dt < 4; ++dt)
#pragma unroll
            for (int r = 0; r < 4; ++r)
                pf[w][mt * 16 + q * 4 + r][dt * 16 + c] = ctxa[mt][dt][r];
    __syncthreads();

    // reduce 4 waves' partials; thread t owns row t>>3, d (t&7)*8
    {
        const int rrow = t >> 3, d0 = (t & 7) * 8;
        float s[8] = {};
#pragma unroll
        for (int ww = 0; ww < 4; ++ww) {
            float4 a0 = *(const float4*)&pf[ww][rrow][d0];
            float4 a1 = *(const float4*)&pf[ww][rrow][d0 + 4];
            s[0] += a0.x; s[1] += a0.y; s[2] += a0.z; s[3] += a0.w;
            s[4] += a1.x; s[5] += a1.y; s[6] += a1.z; s[7] += a1.w;
        }
        u32 p0 = (u32)f2bf(s[0]) | ((u32)f2bf(s[1]) << 16);
        u32 p1 = (u32)f2bf(s[2]) | ((u32)f2bf(s[3]) << 16);
        u32 p2 = (u32)f2bf(s[4]) | ((u32)f2bf(s[5]) << 16);
        u32 p3 = (u32)f2bf(s[6]) | ((u32)f2bf(s[7]) << 16);
        *(uint4*)(ctx + ((size_t)b * S_ + i0 + rrow) * D_ + h * DK_ + d0) =
            make_uint4(p0, p1, p2, p3);
    }
}

// ---------------------------------------------------------------------------
// y = LayerNorm(x + residual_q) * gamma + beta  (one block per row of 1024)
// ---------------------------------------------------------------------------
__global__ __launch_bounds__(256) void ln_kernel(const float* __restrict__ X,
                                                 const float* __restrict__ q,
                                                 const float* __restrict__ gamma,
                                                 const float* __restrict__ beta,
                                                 float* __restrict__ y) {
    const int row = blockIdx.x;
    const int t   = threadIdx.x;
    const size_t base = (size_t)row * D_;

    float4 xv = *(const float4*)(X + base + t * 4);
    float4 qv = *(const float4*)(q + base + t * 4);
    const float x0 = xv.x + qv.x, x1 = xv.y + qv.y;
    const float x2 = xv.z + qv.z, x3 = xv.w + qv.w;

    float sum = x0 + x1 + x2 + x3;
    float sq  = x0 * x0 + x1 * x1 + x2 * x2 + x3 * x3;
#pragma unroll
    for (int o = 32; o > 0; o >>= 1) {
        sum += __shfl_xor(sum, o, 64);
        sq  += __shfl_xor(sq, o, 64);
    }
    __shared__ float red[8];
    const int wv = t >> 6;
    if ((t & 63) == 0) { red[wv] = sum; red[4 + wv] = sq; }
    __syncthreads();
    sum = red[0] + red[1] + red[2] + red[3];
    sq  = red[4] + red[5] + red[6] + red[7];

    const float mu  = sum * (1.0f / 1024.0f);
    const float var = sq * (1.0f / 1024.0f) - mu * mu;
    const float rs  = rsqrtf(var + 1e-5f);

    float4 gv = *(const float4*)(gamma + t * 4);
    float4 bv = *(const float4*)(beta + t * 4);
    float4 o;
    o.x = (x0 - mu) * rs * gv.x + bv.x;
    o.y = (x1 - mu) * rs * gv.y + bv.y;
    o.z = (x2 - mu) * rs * gv.z + bv.z;
    o.w = (x3 - mu) * rs * gv.w + bv.w;
    *(float4*)(y + base + t * 4) = o;
}

extern "C" void kernel_launch(void* const* d_in, const int* in_sizes, int n_in,
                              void* d_out, int out_size, void* d_ws, size_t ws_size,
                              hipStream_t stream) {
    const float* q    = (const float*)d_in[0];
    const float* k    = (const float*)d_in[1];
    const float* v    = (const float*)d_in[2];
    const float* Wq   = (const float*)d_in[3];
    const float* bq   = (const float*)d_in[4];
    const float* Wk   = (const float*)d_in[5];
    const float* bk   = (const float*)d_in[6];
    const float* Wv   = (const float*)d_in[7];
    const float* bv   = (const float*)d_in[8];
    const float* Wfc  = (const float*)d_in[9];
    const float* bfc  = (const float*)d_in[10];
    const float* gamma= (const float*)d_in[11];
    const float* beta = (const float*)d_in[12];

    float* y_out    = (float*)d_out;
    float* attn_out = (float*)d_out + (size_t)B_ * S_ * D_;   // fp32 outputs

    // Workspace 48 MiB (float units):
    //  [0,       2097152)  Qhi bf16 [b][h][s][64]
    //  [2097152, 4194304)  Qlo bf16
    //  [4194304, 6291456)  Khi bf16
    //  [6291456, 8388608)  Klo bf16
    //  [8388608,10485760)  VT  bf16 [b][h][d][s]
    //  [10485760,12582912) ctx bf16 [b][s][1024]
    //  xbuf f32 (16 MiB) reuses Qhi+Qlo region after fused_attn.
    float* ws   = (float*)d_ws;
    u16*  Qhi   = (u16*)(ws);
    u16*  Qlo   = (u16*)(ws + 2097152);
    u16*  Khi   = (u16*)(ws + 4194304);
    u16*  Klo   = (u16*)(ws + 6291456);
    u16*  VTb   = (u16*)(ws + 8388608);
    u16*  ctxb  = (u16*)(ws + 10485760);
    float* xbuf = ws;                  // reuse (Q splits dead after fused_attn)

    const dim3 gg(8, 32), bb(256);     // 128x128 tiles
    gemm_mfma<1, 0><<<gg, bb, 0, stream>>>(q, Wq, bq, nullptr, Qhi, Qlo, 4096, 1024, 1024);
    gemm_mfma<1, 0><<<gg, bb, 0, stream>>>(k, Wk, bk, nullptr, Khi, Klo, 4096, 1024, 1024);
    gemm_mfma<2, 0><<<gg, bb, 0, stream>>>(v, Wv, bv, nullptr, VTb, nullptr, 4096, 1024, 1024);

    fused_attn<<<dim3(32, 64), bb, 0, stream>>>(Qhi, Qlo, Khi, Klo, VTb, attn_out, ctxb);

    gemm_mfma<0, 1><<<gg, bb, 0, stream>>>(ctxb, Wfc, bfc, xbuf, nullptr, nullptr, 4096, 1024, 1024);
    ln_kernel<<<4096, 256, 0, stream>>>(xbuf, q, gamma, beta, y_out);
}